// Round 19
// baseline (348.686 us; speedup 1.0000x reference)
//
#include <hip/hip_runtime.h>
#include <math.h>

// LinearAttention (2nd-order derivative-expanded DeltaNet-like), fp32.
// B=2,H=16,S=2048,D=64; n=2; CHUNK=64 -> 128 virtual rows/chunk.
// la_gram:   per-chunk packed Gram -> gG.
// la_p1scan: FUSED: blocks 0-31 = per-pair WAVE-LEVEL h-scan (1 wave, no
//            barriers, readlane broadcasts, LDS-transpose norm, h stored ^T);
//            blocks 32+ = WY-solve producers (nc-major). Flag handoff via
//            __hip_atomic acquire/release (agent scope).
// la_out:    all outputs, fully parallel (reads h^T; h column in regs).
// Fallbacks: phase1g+scan+out (needA), phase1g+phase2 (needB), phase1f+phase2.

namespace {
constexpr int PAIRS = 32;   // B*H
constexpr int SLEN  = 2048;
constexpr int D     = 64;
constexpr int CK    = 64;
constexpr int CN    = 128;
constexpr int NCH   = 32;
constexpr int NB2   = 16;   // fallback phase 2
constexpr int NP    = 5;    // fallback phase 2
constexpr size_t YWORDS = (size_t)PAIRS * NCH * CN * CN;   // 16M floats
constexpr int GP = 2145;
constexpr size_t GGW = (size_t)PAIRS * NCH * GP;
constexpr size_t HGW = (size_t)PAIRS * (NCH + 1) * D * D;  // h^T slots
constexpr size_t FLW = PAIRS * NCH;                        // flags (uint)

__device__ __forceinline__ float stab1(float x) {
    float y = __builtin_amdgcn_fmed3f(x, -10000.f, 10000.f);
    return (x != x) ? 0.f : y;
}
__device__ __forceinline__ int kidx(int a, int f4) {
    return a * 68 + 4 * (f4 ^ ((a >> 2) & 3));
}
__device__ __forceinline__ void bar_lds() {
    asm volatile("s_waitcnt lgkmcnt(0)\n\ts_barrier" ::: "memory");
}
__device__ __forceinline__ float rdlane(float v, int l) {
    return __int_as_float(__builtin_amdgcn_readlane(__float_as_int(v), l));
}
} // namespace

// ---------------- la_gram ----------------
__global__ __launch_bounds__(256, 2)
void la_gram(const float* __restrict__ kg, float* __restrict__ gG)
{
    __shared__ float kstf[65 * 68];
    const int blk = blockIdx.x;
    const int p = blk >> 5, nc = blk & 31;
    const int tid = threadIdx.x;
    const int baseT = nc * CK;
    const float* kp = kg + (size_t)p * SLEN * D;

    for (int u = tid; u < 65 * 16; u += 256) {
        int a = u >> 4, f4 = u & 15;
        int src = baseT - 1 + a;
        float4 val = float4{0.f, 0.f, 0.f, 0.f};
        if (src >= 0) val = ((const float4*)(kp + (size_t)src * D))[f4];
        *(float4*)&kstf[kidx(a, f4)] = val;
    }
    __syncthreads();

    float* gps = gG + (size_t)blk * GP;
    for (int tt = tid; tt < 17 * 17; tt += 256) {
        int ta = tt / 17, tb = tt % 17;
        if (tb > ta) continue;
        int a0 = ta * 4, b0 = tb * 4;
        float acc[4][4] = {};
        for (int d4 = 0; d4 < 16; ++d4) {
            float4 av[4], bv[4];
            #pragma unroll
            for (int r = 0; r < 4; ++r) {
                av[r] = *(const float4*)&kstf[kidx(min(a0 + r, 64), d4)];
                bv[r] = *(const float4*)&kstf[kidx(min(b0 + r, 64), d4)];
            }
            #pragma unroll
            for (int r = 0; r < 4; ++r)
                #pragma unroll
                for (int c = 0; c < 4; ++c)
                    acc[r][c] += av[r].x * bv[c].x + av[r].y * bv[c].y
                               + av[r].z * bv[c].z + av[r].w * bv[c].w;
        }
        #pragma unroll
        for (int r = 0; r < 4; ++r)
            #pragma unroll
            for (int c = 0; c < 4; ++c) {
                int a = a0 + r, b = b0 + c;
                if (a <= 64 && b <= a)
                    gps[a * (a + 1) / 2 + b] = acc[r][c];
            }
    }
}

// ---------------- la_p1scan: fused producers + wave-level scan --------------
// grid = PAIRS + PAIRS*NCH*2 (2080), 256 thr.
// blk < PAIRS: scan for pair p=blk -- ONE wave, no barriers.
// blk >= PAIRS: producer; idx=blk-PAIRS, nc=idx>>6, p=(idx&63)>>1, half=idx&1.
__global__ __launch_bounds__(256, 3)
void la_p1scan(const float* __restrict__ kg, const float* __restrict__ vg,
               const float* __restrict__ bg, float* __restrict__ ws,
               const float* __restrict__ gG, float* __restrict__ hg,
               unsigned int* __restrict__ flags)
{
    __shared__ char shm[47808];
    const int blk = blockIdx.x;
    const int tid = threadIdx.x;

    if (blk < PAIRS) {
        // ============ wave-level scan consumer (wave 0 only) ============
        const int p = blk;
        float* hp = hg + (size_t)p * (NCH + 1) * (D * D);
        for (int idx = tid; idx < D * D; idx += 256) hp[idx] = 0.f;  // h^T[0]=0
        if (tid >= 64) return;
        const int lane = tid;
        const float* Yp = ws + (size_t)p * NCH * (CN * CN);
        const unsigned int* fl = flags + (size_t)p * NCH;
        float* tr  = (float*)shm;        // [64*65] transpose scratch
        float* nsh = tr + 64 * 65;       // [64] per-row scale

        float hs[64];                    // h[d][lane], d = 0..63
        #pragma unroll
        for (int d = 0; d < 64; ++d) hs[d] = 0.f;

        for (int nc = 0; nc < NCH; ++nc) {
            while (__hip_atomic_load(&fl[nc], __ATOMIC_ACQUIRE,
                                     __HIP_MEMORY_SCOPE_AGENT) < 2u)
                __builtin_amdgcn_s_sleep(8);
            const float* Yc = Yp + (size_t)nc * (CN * CN);
            const float w0v = Yc[126 * CN + lane];
            const float u0v = Yc[126 * CN + 64 + lane];
            const float w1v = Yc[127 * CN + lane];
            const float u1v = Yc[127 * CN + 64 + lane];

            // kh0 = sum_d w0[d]*h[d][lane]  (readlane broadcasts, 4 chains)
            float a0 = 0.f, a1 = 0.f, a2 = 0.f, a3 = 0.f;
            #pragma unroll
            for (int d = 0; d < 64; d += 4) {
                a0 += rdlane(w0v, d)     * hs[d];
                a1 += rdlane(w0v, d + 1) * hs[d + 1];
                a2 += rdlane(w0v, d + 2) * hs[d + 2];
                a3 += rdlane(w0v, d + 3) * hs[d + 3];
            }
            const float uv0 = u0v - ((a0 + a1) + (a2 + a3));

            // st1 in place + kh1 (single fused pass)
            float b0 = 0.f, b1 = 0.f, b2 = 0.f, b3 = 0.f;
            #pragma unroll
            for (int d = 0; d < 64; d += 4) {
                hs[d]     = stab1(hs[d]     + rdlane(w0v, d)     * uv0);
                b0 += rdlane(w1v, d)     * hs[d];
                hs[d + 1] = stab1(hs[d + 1] + rdlane(w0v, d + 1) * uv0);
                b1 += rdlane(w1v, d + 1) * hs[d + 1];
                hs[d + 2] = stab1(hs[d + 2] + rdlane(w0v, d + 2) * uv0);
                b2 += rdlane(w1v, d + 2) * hs[d + 2];
                hs[d + 3] = stab1(hs[d + 3] + rdlane(w0v, d + 3) * uv0);
                b3 += rdlane(w1v, d + 3) * hs[d + 3];
            }
            const float uv1 = u1v - ((b0 + b1) + (b2 + b3));

            // st2 in place
            #pragma unroll
            for (int d = 0; d < 64; ++d)
                hs[d] = stab1(hs[d] + rdlane(w1v, d) * uv1);

            // row norms via wave-synchronous LDS transpose (no barriers)
            #pragma unroll
            for (int d = 0; d < 64; ++d) tr[d * 65 + lane] = hs[d];
            float ssum = 0.f;
            #pragma unroll
            for (int e = 0; e < 64; ++e) {
                float v = tr[lane * 65 + e];
                ssum += v * v;
            }
            {
                float xn = __builtin_amdgcn_sqrtf(ssum) + 1e-6f;
                nsh[lane] = 2.f * __builtin_amdgcn_rcpf(xn);
            }
            // gelu: h'[d][lane] = 0.25*x*y*(1+tanh), y = x*nsh[d]
            float* ho = hp + (size_t)(nc + 1) * (D * D) + (size_t)lane * 64;
            #pragma unroll
            for (int d = 0; d < 64; ++d) {
                float x  = hs[d];
                float y  = x * nsh[d];
                float y2 = y * y;
                float e  = __builtin_amdgcn_exp2f(y * (2.3022078f + 0.1029432f * y2));
                float th = (e - 1.f) * __builtin_amdgcn_rcpf(e + 1.f);
                hs[d] = 0.25f * x * y * (1.f + th);
            }
            #pragma unroll
            for (int k = 0; k < 16; ++k)
                *(float4*)&ho[4 * k] =
                    float4{hs[4 * k], hs[4 * k + 1], hs[4 * k + 2], hs[4 * k + 3]};
        }
        return;
    }

    // ================= producer (WY solve) =================
    float (*Ysh)[64]   = (float(*)[64])shm;                      // [128][64]
    float (*scm)[CN][8] = (float(*)[CN][8])(shm + 32768);        // [2][128][8]
    float (*redsh)[66] = (float(*)[66])(shm + 40960);            // [24][66]
    float* bq4 = (float*)(shm + 47296);                          // [64]
    float* bh  = bq4 + 64;                                       // [64]

    const int idx  = blk - PAIRS;
    const int nc   = idx >> 6;
    const int p    = (idx & 63) >> 1;
    const int half = idx & 1;
    const int col  = tid & 63;
    const int m    = tid >> 6;
    const int baseT = nc * CK;
    const float* kp = kg + (size_t)p * SLEN * D;
    const float* vp = vg + (size_t)p * SLEN * D;
    const float* bp = bg + (size_t)p * SLEN;
    const float* gps = gG + (size_t)(p * NCH + nc) * GP;

    if (tid < CK) {
        float bv = bp[baseT + tid];
        bq4[tid] = 0.25f * bv;
        bh[tid]  = 0.5f  * bv;
    }
    __syncthreads();

    const float* srcBase = half ? vp : kp;
    for (int u = tid; u < CN * 16; u += 256) {
        int i = u >> 4, f4 = u & 15;
        int ci = i >> 1, si = i & 1;
        float sc = si ? bh[ci] : -bh[ci];
        int srcT = baseT + ci - si;
        float4 val = float4{0.f, 0.f, 0.f, 0.f};
        if (srcT >= 0) val = ((const float4*)(srcBase + (size_t)srcT * D))[f4];
        val.x *= sc; val.y *= sc; val.z *= sc; val.w *= sc;
        *(float4*)&Ysh[i][f4 * 4] = val;
    }
    for (int e = tid; e < 64; e += 256) {
        int j = e >> 3, r = e & 7;
        int ai = (r >> 1) - (r & 1) + 1;
        int aj = (j >> 1) - (j & 1) + 1;
        int amax = max(ai, aj), amin = min(ai, aj);
        float sgn = ((r ^ j) & 1) ? -1.f : 1.f;
        scm[0][j][r] = sgn * bq4[r >> 1] * gps[amax * (amax + 1) / 2 + amin];
    }
    __syncthreads();

    #pragma unroll
    for (int g = 0; g < 16; ++g) {
        const int buf = g & 1;
        float acc[8] = {};
        #pragma unroll
        for (int jj = 0; jj < 2 * g; ++jj) {
            const int j = m + 4 * jj;
            float yv = Ysh[j][col];
            const float4 a03 = *(const float4*)&scm[buf][j][0];
            const float4 a47 = *(const float4*)&scm[buf][j][4];
            acc[0] += a03.x * yv; acc[1] += a03.y * yv;
            acc[2] += a03.z * yv; acc[3] += a03.w * yv;
            acc[4] += a47.x * yv; acc[5] += a47.y * yv;
            acc[6] += a47.z * yv; acc[7] += a47.w * yv;
        }
        if (m > 0) {
            #pragma unroll
            for (int r = 0; r < 8; ++r) redsh[(m - 1) * 8 + r][col] = acc[r];
        }
        bar_lds();
        if (m == 0) {
            if (g > 0) {
                #pragma unroll
                for (int r = 0; r < 8; ++r)
                    acc[r] += redsh[r][col] + redsh[8 + r][col] + redsh[16 + r][col];
            }
            float yn[8];
            #pragma unroll
            for (int r = 0; r < 8; ++r) {
                float val = Ysh[8 * g + r][col] - acc[r];
                #pragma unroll
                for (int rp = 0; rp < 8; ++rp)
                    if (rp < r) val -= scm[buf][8 * g + rp][r] * yn[rp];
                yn[r] = val;
                Ysh[8 * g + r][col] = val;
            }
        } else if (g < 15) {
            const int T = g + 1, bufB = T & 1;
            const int nel = 8 * (8 * T + 8);
            constexpr int MAXIT = 6;
            const int nit = (nel + 191) / 192;
            #pragma unroll
            for (int it = 0; it < MAXIT; ++it) {
                if (it < nit) {
                    const int e = (tid - 64) + 192 * it;
                    if (e < nel) {
                        int j = e >> 3, r = e & 7;
                        int i = 8 * T + r;
                        int ai = (i >> 1) - (i & 1) + 1;
                        int aj = (j >> 1) - (j & 1) + 1;
                        int amax = max(ai, aj), amin = min(ai, aj);
                        float sgn = ((i ^ j) & 1) ? -1.f : 1.f;
                        scm[bufB][j][r] =
                            sgn * bq4[i >> 1] * gps[amax * (amax + 1) / 2 + amin];
                    }
                }
            }
        }
        bar_lds();
    }

    float* gY = ws + (size_t)(p * NCH + nc) * (CN * CN) + half * 64;
    for (int u = tid; u < CN * 16; u += 256) {
        int r = u >> 4, f4 = u & 15;
        *(float4*)&gY[r * CN + f4 * 4] = *(const float4*)&Ysh[r][f4 * 4];
    }
    __syncthreads();   // drain stores before release
    if (tid == 0)
        __hip_atomic_fetch_add(&flags[p * NCH + nc], 1u, __ATOMIC_RELEASE,
                               __HIP_MEMORY_SCOPE_AGENT);
}

// ---------------- la_out: all outputs, fully parallel (reads h^T) -----------
__global__ __launch_bounds__(512)
void la_out(const float* __restrict__ qg, const float* __restrict__ ws,
            const float* __restrict__ hg, float* __restrict__ outg)
{
    __shared__ float hT[64 * 68];
    __shared__ float wbr[8][3][64];

    const int blk = blockIdx.x;
    const int p = blk >> 5, nc = blk & 31;
    const int tid = threadIdx.x;
    const int w = tid >> 6, lane = tid & 63;

    const float* Yc = ws + (size_t)(p * NCH + nc) * (CN * CN);
    const float* hp = hg + ((size_t)p * (NCH + 1) + nc) * (D * D);  // h^T [e][d]
    const float* qp = qg + (size_t)p * SLEN * D;
    float* op = outg + (size_t)p * SLEN * D;

    for (int idx = tid; idx < D * D; idx += 512)
        hT[(idx >> 6) * 68 + (idx & 63)] = hp[idx];
    __syncthreads();

    float4 hr[16];   // h[4k..4k+3][lane]
    #pragma unroll
    for (int k = 0; k < 16; ++k)
        hr[k] = *(const float4*)&hT[lane * 68 + 4 * k];

    float w0n, u0n, w1n, u1n, qn;
    {
        const int c = w, t = nc * CK + c;
        w0n = Yc[(size_t)(2 * c) * CN + lane];
        u0n = Yc[(size_t)(2 * c) * CN + 64 + lane];
        w1n = Yc[(size_t)(2 * c + 1) * CN + lane];
        u1n = Yc[(size_t)(2 * c + 1) * CN + 64 + lane];
        qn  = qp[(size_t)((t > 0) ? t - 1 : 0) * D + lane];
    }

    for (int it = 0; it < 8; ++it) {
        const int c = it * 8 + w;
        const int t = nc * CK + c;
        const float w0v = w0n, u0l = u0n, w1v = w1n, u1l = u1n, qv = qn;
        if (it < 7) {
            const int c2 = (it + 1) * 8 + w;
            w0n = Yc[(size_t)(2 * c2) * CN + lane];
            u0n = Yc[(size_t)(2 * c2) * CN + 64 + lane];
            w1n = Yc[(size_t)(2 * c2 + 1) * CN + lane];
            u1n = Yc[(size_t)(2 * c2 + 1) * CN + 64 + lane];
            qn  = qp[(size_t)(nc * CK + c2 - 1) * D + lane];
        }

        wbr[w][0][lane] = w0v;
        wbr[w][1][lane] = w1v;
        wbr[w][2][lane] = qv;

        float uv0 = u0l;
        #pragma unroll
        for (int k = 0; k < 16; ++k) {
            float4 wb = *(const float4*)&wbr[w][0][4 * k];
            uv0 -= (wb.x * hr[k].x + wb.y * hr[k].y)
                 + (wb.z * hr[k].z + wb.w * hr[k].w);
        }
        float kh = 0.f, oa = 0.f;
        #pragma unroll
        for (int k = 0; k < 16; ++k) {
            float4 wb0 = *(const float4*)&wbr[w][0][4 * k];
            float4 wb1 = *(const float4*)&wbr[w][1][4 * k];
            float4 qb  = *(const float4*)&wbr[w][2][4 * k];
            float st0 = stab1(hr[k].x + wb0.x * uv0);
            float st1 = stab1(hr[k].y + wb0.y * uv0);
            float st2 = stab1(hr[k].z + wb0.z * uv0);
            float st3 = stab1(hr[k].w + wb0.w * uv0);
            kh += (wb1.x * st0 + wb1.y * st1) + (wb1.z * st2 + wb1.w * st3);
            oa += (qb.x * st0 + qb.y * st1) + (qb.z * st2 + qb.w * st3);
        }
        float uv1 = u1l - kh;
        float outv = 0.5f * (qv * uv1 + oa);
        op[(size_t)t * D + lane] = (t > 0) ? outv : 0.f;
    }
}

// ---------------- la_phase1g (fallback separate producer) ----------------
__global__ __launch_bounds__(256, 3)
void la_phase1g(const float* __restrict__ kg, const float* __restrict__ vg,
                const float* __restrict__ bg, float* __restrict__ ws,
                const float* __restrict__ gG)
{
    __shared__ float Ysh[CN][64];
    __shared__ float scm[2][CN][8];
    __shared__ float redsh[24][66];
    __shared__ float bq4[CK], bh[CK];

    const int blk  = blockIdx.x;
    const int p    = blk >> 6;
    const int nc   = (blk >> 1) & 31;
    const int half = blk & 1;
    const int tid  = threadIdx.x;
    const int col  = tid & 63;
    const int m    = tid >> 6;
    const int baseT = nc * CK;
    const float* kp = kg + (size_t)p * SLEN * D;
    const float* vp = vg + (size_t)p * SLEN * D;
    const float* bp = bg + (size_t)p * SLEN;
    const float* gps = gG + (size_t)(p * NCH + nc) * GP;

    if (tid < CK) {
        float bv = bp[baseT + tid];
        bq4[tid] = 0.25f * bv;
        bh[tid]  = 0.5f  * bv;
    }
    __syncthreads();

    const float* srcBase = half ? vp : kp;
    for (int u = tid; u < CN * 16; u += 256) {
        int i = u >> 4, f4 = u & 15;
        int ci = i >> 1, si = i & 1;
        float sc = si ? bh[ci] : -bh[ci];
        int srcT = baseT + ci - si;
        float4 val = float4{0.f, 0.f, 0.f, 0.f};
        if (srcT >= 0) val = ((const float4*)(srcBase + (size_t)srcT * D))[f4];
        val.x *= sc; val.y *= sc; val.z *= sc; val.w *= sc;
        *(float4*)&Ysh[i][f4 * 4] = val;
    }
    for (int e = tid; e < 64; e += 256) {
        int j = e >> 3, r = e & 7;
        int ai = (r >> 1) - (r & 1) + 1;
        int aj = (j >> 1) - (j & 1) + 1;
        int amax = max(ai, aj), amin = min(ai, aj);
        float sgn = ((r ^ j) & 1) ? -1.f : 1.f;
        scm[0][j][r] = sgn * bq4[r >> 1] * gps[amax * (amax + 1) / 2 + amin];
    }
    __syncthreads();

    #pragma unroll
    for (int g = 0; g < 16; ++g) {
        const int buf = g & 1;
        float acc[8] = {};
        #pragma unroll
        for (int jj = 0; jj < 2 * g; ++jj) {
            const int j = m + 4 * jj;
            float yv = Ysh[j][col];
            const float4 a03 = *(const float4*)&scm[buf][j][0];
            const float4 a47 = *(const float4*)&scm[buf][j][4];
            acc[0] += a03.x * yv; acc[1] += a03.y * yv;
            acc[2] += a03.z * yv; acc[3] += a03.w * yv;
            acc[4] += a47.x * yv; acc[5] += a47.y * yv;
            acc[6] += a47.z * yv; acc[7] += a47.w * yv;
        }
        if (m > 0) {
            #pragma unroll
            for (int r = 0; r < 8; ++r) redsh[(m - 1) * 8 + r][col] = acc[r];
        }
        bar_lds();
        if (m == 0) {
            if (g > 0) {
                #pragma unroll
                for (int r = 0; r < 8; ++r)
                    acc[r] += redsh[r][col] + redsh[8 + r][col] + redsh[16 + r][col];
            }
            float yn[8];
            #pragma unroll
            for (int r = 0; r < 8; ++r) {
                float val = Ysh[8 * g + r][col] - acc[r];
                #pragma unroll
                for (int rp = 0; rp < 8; ++rp)
                    if (rp < r) val -= scm[buf][8 * g + rp][r] * yn[rp];
                yn[r] = val;
                Ysh[8 * g + r][col] = val;
            }
        } else if (g < 15) {
            const int T = g + 1, bufB = T & 1;
            const int nel = 8 * (8 * T + 8);
            constexpr int MAXIT = 6;
            const int nit = (nel + 191) / 192;
            #pragma unroll
            for (int it = 0; it < MAXIT; ++it) {
                if (it < nit) {
                    const int e = (tid - 64) + 192 * it;
                    if (e < nel) {
                        int j = e >> 3, r = e & 7;
                        int i = 8 * T + r;
                        int ai = (i >> 1) - (i & 1) + 1;
                        int aj = (j >> 1) - (j & 1) + 1;
                        int amax = max(ai, aj), amin = min(ai, aj);
                        float sgn = ((i ^ j) & 1) ? -1.f : 1.f;
                        scm[bufB][j][r] =
                            sgn * bq4[i >> 1] * gps[amax * (amax + 1) / 2 + amin];
                    }
                }
            }
        }
        bar_lds();
    }

    float* gY = ws + (size_t)(p * NCH + nc) * (CN * CN) + half * 64;
    for (int u = tid; u < CN * 16; u += 256) {
        int r = u >> 4, f4 = u & 15;
        *(float4*)&gY[r * CN + f4 * 4] = *(const float4*)&Ysh[r][f4 * 4];
    }
}

// ---------------- la_scan (fallback; writes h TRANSPOSED) ----------------
__global__ __launch_bounds__(512, 1)
void la_scan(const float* __restrict__ ws, float* __restrict__ hg)
{
    __shared__ float w0s[64], u0s[64], w1s[64], u1s[64];
    __shared__ float pA[8][64], pB[8][64];
    __shared__ float hsh2[64][67];

    const int p = blockIdx.x;
    const int tid = threadIdx.x;
    const int w = tid >> 6, lane = tid & 63;
    const int hd = tid >> 3, he0 = (tid & 7) * 8;
    const float* Yp = ws + (size_t)p * NCH * (CN * CN);
    float* hp = hg + (size_t)p * (NCH + 1) * (D * D);

    for (int idx = tid; idx < D * D; idx += 512) hp[idx] = 0.f;
    for (int idx = tid; idx < 64 * 67; idx += 512) (&hsh2[0][0])[idx] = 0.f;

    auto stagew = [&](float v) {
        if (tid < 64)       w0s[tid] = v;
        else if (tid < 128) u0s[tid - 64] = v;
        else if (tid < 192) w1s[tid - 128] = v;
        else if (tid < 256) u1s[tid - 192] = v;
    };
    {
        float v = 0.f;
        if (tid < 256) v = Yp[(size_t)(126 + (tid >> 7)) * CN + (tid & 127)];
        stagew(v);
    }
    float hs[8];
    #pragma unroll
    for (int j = 0; j < 8; ++j) hs[j] = 0.f;
    __syncthreads();

    for (int nc = 0; nc < NCH; ++nc) {
        float pf = 0.f;
        if (nc + 1 < NCH && tid < 256)
            pf = Yp[(size_t)(nc + 1) * (CN * CN)
                    + (size_t)(126 + (tid >> 7)) * CN + (tid & 127)];

        float s = 0.f;
        #pragma unroll
        for (int j = 0; j < 8; ++j) s += w0s[8 * w + j] * hs[j];
        pA[w][lane] = s;
        bar_lds();

        float sum = 0.f;
        #pragma unroll
        for (int wv = 0; wv < 8; ++wv) sum += pA[wv][lane];
        const float uv0 = u0s[lane] - sum;

        float st1[8];
        float s2 = 0.f;
        #pragma unroll
        for (int j = 0; j < 8; ++j) {
            st1[j] = stab1(hs[j] + w0s[8 * w + j] * uv0);
            s2 += w1s[8 * w + j] * st1[j];
        }
        pB[w][lane] = s2;
        bar_lds();

        float sum2 = 0.f;
        #pragma unroll
        for (int wv = 0; wv < 8; ++wv) sum2 += pB[wv][lane];
        const float uv1 = u1s[lane] - sum2;
        #pragma unroll
        for (int j = 0; j < 8; ++j)
            hsh2[8 * w + j][lane] = stab1(st1[j] + w1s[8 * w + j] * uv1);
        bar_lds();

        {
            float st2v[8];
            float ssum = 0.f;
            #pragma unroll
            for (int j = 0; j < 8; ++j) {
                st2v[j] = hsh2[hd][he0 + j];
                ssum += st2v[j] * st2v[j];
            }
            ssum += __shfl_xor(ssum, 1);
            ssum += __shfl_xor(ssum, 2);
            ssum += __shfl_xor(ssum, 4);
            float xn = __builtin_amdgcn_sqrtf(ssum) + 1e-6f;
            float sc2 = 2.f * __builtin_amdgcn_rcpf(xn);
            float* hob = hp + (size_t)(nc + 1) * (D * D);
            #pragma unroll
            for (int j = 0; j < 8; ++j) {
                float x  = st2v[j];
                float y  = x * sc2;
                float y2 = y * y;
                float e  = __builtin_amdgcn_exp2f(y * (2.3022078f + 0.1029432f * y2));
                float th = (e - 1.f) * __builtin_amdgcn_rcpf(e + 1.f);
                float hn = 0.25f * x * y * (1.f + th);
                hsh2[hd][he0 + j] = hn;
                hob[(size_t)(he0 + j) * 64 + hd] = hn;   // transposed store
            }
        }
        if (nc + 1 < NCH) stagew(pf);
        bar_lds();
        #pragma unroll
        for (int j = 0; j < 8; ++j) hs[j] = hsh2[8 * w + j][lane];
    }
}

// ---------------- la_phase1f + la_phase2 (deep fallbacks) ----------------
__global__ __launch_bounds__(256, 2)
void la_phase1f(const float* __restrict__ kg, const float* __restrict__ vg,
                const float* __restrict__ bg, float* __restrict__ ws)
{
    __shared__ float Ysh[CN][64];
    __shared__ float Gm[65][66];
    __shared__ char  ureg[17680];
    __shared__ float bq4[CK], bh[CK];

    float* kstf = (float*)ureg;
    float* scm  = (float*)ureg;
    float (*redsh)[66] = (float(*)[66])(ureg + 8192);

    const int blk  = blockIdx.x;
    const int p    = blk >> 6;
    const int nc   = (blk >> 1) & 31;
    const int half = blk & 1;
    const int tid  = threadIdx.x;
    const int baseT = nc * CK;
    const float* kp = kg + (size_t)p * SLEN * D;
    const float* vp = vg + (size_t)p * SLEN * D;
    const float* bp = bg + (size_t)p * SLEN;

    for (int u = tid; u < 65 * 16; u += 256) {
        int a = u >> 4, f4 = u & 15;
        int src = baseT - 1 + a;
        float4 val = float4{0.f, 0.f, 0.f, 0.f};
        if (src >= 0) val = ((const float4*)(kp + (size_t)src * D))[f4];
        *(float4*)&kstf[kidx(a, f4)] = val;
    }
    if (tid < CK) {
        float bv = bp[baseT + tid];
        bq4[tid] = 0.25f * bv;
        bh[tid]  = 0.5f  * bv;
    }
    __syncthreads();

    for (int u = tid; u < CN * 16; u += 256) {
        int i = u >> 4, f4 = u & 15;
        int ci = i >> 1, si = i & 1;
        float sc = si ? bh[ci] : -bh[ci];
        float4 val = float4{0.f, 0.f, 0.f, 0.f};
        if (half == 0) {
            val = *(const float4*)&kstf[kidx(ci - si + 1, f4)];
        } else {
            int srcT = baseT + ci - si;
            if (srcT >= 0) val = ((const float4*)(vp + (size_t)srcT * D))[f4];
        }
        val.x *= sc; val.y *= sc; val.z *= sc; val.w *= sc;
        *(float4*)&Ysh[i][f4 * 4] = val;
    }

    for (int tt = tid; tt < 17 * 17; tt += 256) {
        int ta = tt / 17, tb = tt % 17;
        if (tb > ta) continue;
        int a0 = ta * 4, b0 = tb * 4;
        float acc[4][4] = {};
        for (int d4 = 0; d4 < 16; ++d4) {
            float4 av[4], bv[4];
            #pragma unroll
            for (int r = 0; r < 4; ++r) {
                av[r] = *(const float4*)&kstf[kidx(min(a0 + r, 64), d4)];
                bv[r] = *(const float4*)&kstf[kidx(min(b0 + r, 64), d4)];
            }
            #pragma unroll
            for (int r = 0; r < 4; ++r)
                #pragma unroll
                for (int c = 0; c < 4; ++c)
                    acc[r][c] += av[r].x * bv[c].x + av[r].y * bv[c].y
                               + av[r].z * bv[c].z + av[r].w * bv[c].w;
        }
        #pragma unroll
        for (int r = 0; r < 4; ++r)
            #pragma unroll
            for (int c = 0; c < 4; ++c)
                if (a0 + r <= 64 && b0 + c <= 64) {
                    Gm[a0 + r][b0 + c] = acc[r][c];
                    Gm[b0 + c][a0 + r] = acc[r][c];
                }
    }
    __syncthreads();

    auto stripf = [&](int g, int t0, int tstride) {
        int buf = g & 1;
        int jmax = 8 * g + 8;
        for (int e = t0; e < 8 * jmax; e += tstride) {
            int j = e >> 3, r = e & 7;
            int i = 8 * g + r;
            int ai = (i >> 1) - (i & 1) + 1;
            int aj = (j >> 1) - (j & 1) + 1;
            float sgn = ((i ^ j) & 1) ? -1.f : 1.f;
            scm[(buf * CN + j) * 8 + r] = sgn * bq4[i >> 1] * Gm[ai][aj];
        }
    };

    stripf(0, tid, 256);
    __syncthreads();

    const int col = tid & 63;
    const int m   = tid >> 6;
    for (int g = 0; g < 16; ++g) {
        const int buf = g & 1;
        float acc[8] = {};
        for (int j = m; j < 8 * g; j += 4) {
            float yv = Ysh[j][col];
            const float4 a03 = *(const float4*)&scm[(buf * CN + j) * 8];
            const float4 a47 = *(const float4*)&scm[(buf * CN + j) * 8 + 4];
            acc[0] += a03.x * yv; acc[1] += a03.y * yv;
            acc[2] += a03.z * yv; acc[3] += a03.w * yv;
            acc[4] += a47.x * yv; acc[5] += a47.y * yv;
            acc[6] += a47.z * yv; acc[7] += a47.w * yv;
        }
        if (m > 0) {
            #pragma unroll
            for (int r = 0; r < 8; ++r) redsh[(m - 1) * 8 + r][col] = acc[r];
        }
        __syncthreads();
        if (m == 0) {
            if (g > 0) {
                #pragma unroll
                for (int r = 0; r < 8; ++r)
                    acc[r] += redsh[r][col] + redsh[8 + r][col] + redsh[16 + r][col];
            }
            float yn[8];
            #pragma unroll
            for (int r = 0; r < 8; ++r) {
                float val = Ysh[8 * g + r][col] - acc[r];
                #pragma unroll
                for (int rp = 0; rp < 8; ++rp)
                    if (rp < r) val -= scm[(buf * CN + 8 * g + rp) * 8 + r] * yn[rp];
                yn[r] = val;
                Ysh[8 * g + r][col] = val;
            }
        } else if (g < 15) {
            stripf(g + 1, tid - 64, 192);
        }
        __syncthreads();
    }

    float* gY = ws + (size_t)(p * NCH + nc) * (CN * CN) + half * 64;
    for (int u = tid; u < CN * 16; u += 256) {
        int r = u >> 4, f4 = u & 15;
        *(float4*)&gY[r * CN + f4 * 4] = *(const float4*)&Ysh[r][f4 * 4];
    }
}

__global__ __launch_bounds__(512, 4)
void la_phase2(const float* __restrict__ qg, const float* __restrict__ ws,
               float* __restrict__ outg)
{
    __shared__ float WU[2][NP][256];
    __shared__ float Qs[2][NP][64];
    __shared__ float pR1[8][NP][64];
    __shared__ float pKH[8][NP][64];
    __shared__ float pOA[8][NP][64];
    __shared__ float UV0[NP][64];
    __shared__ float UV1r[64];
    __shared__ float hsh[64][67];

    const int blk  = blockIdx.x;
    const int p    = blk >> 4, nb = blk & 15;
    const int tid  = threadIdx.x;
    const int w    = tid >> 6, lane = tid & 63;
    const int hd   = tid >> 3;
    const int he0  = (tid & 7) * 8;

    const float* qp = qg + (size_t)p * SLEN * D;
    float* op = outg + (size_t)p * SLEN * D;
    const float* wsbase = ws + (size_t)p * NCH * (CN * CN);

    const int cMain = nb * 4 + w;

    float4 wuR = float4{0.f, 0.f, 0.f, 0.f};
    float  qR  = 0.f;

    auto stage_load = [&](int nc) {
        const float* gY = wsbase + (size_t)nc * (CN * CN);
        if (w < 4) {
            wuR = *(const float4*)(gY + (size_t)(2 * cMain) * CN + lane * 4);
            int t = nc * CK + cMain;
            qR = qp[(size_t)((t > 0) ? t - 1 : 0) * D + lane];
        } else if (w == 4) {
            wuR = *(const float4*)(gY + (size_t)126 * CN + lane * 4);
            qR = qp[(size_t)(nc * CK + 62) * D + lane];
        }
    };
    auto stage_write = [&](int buf) {
        if (w < NP) {
            *(float4*)&WU[buf][w][lane * 4] = wuR;
            Qs[buf][w][lane] = qR;
        }
    };

    for (int idx = tid; idx < 64 * 67; idx += 512) (&hsh[0][0])[idx] = 0.f;
    stage_load(0);
    stage_write(0);
    __syncthreads();

    for (int nc = 0; nc < NCH; ++nc) {
        const int buf = nc & 1;
        float hs[8];
        #pragma unroll
        for (int j = 0; j < 8; ++j) hs[j] = hsh[8 * w + j][lane];
        if (nc + 1 < NCH) stage_load(nc + 1);

        #pragma unroll
        for (int P = 0; P < NP; ++P) {
            float4 a = *(const float4*)&WU[buf][P][8 * w];
            float4 b = *(const float4*)&WU[buf][P][8 * w + 4];
            pR1[w][P][lane] =
                  ((a.x * hs[0] + a.y * hs[1]) + (a.z * hs[2] + a.w * hs[3]))
                + ((b.x * hs[4] + b.y * hs[5]) + (b.z * hs[6] + b.w * hs[7]));
        }
        __syncthreads();

        if (w < NP) {
            float s = 0.f;
            #pragma unroll
            for (int wv = 0; wv < 8; ++wv) s += pR1[wv][w][lane];
            UV0[w][lane] = WU[buf][w][64 + lane] - s;
        }
        __syncthreads();

        #pragma unroll
        for (int P = 0; P < NP; ++P) {
            float uv0 = UV0[P][lane];
            float4 w0a = *(const float4*)&WU[buf][P][8 * w];
            float4 w0b = *(const float4*)&WU[buf][P][8 * w + 4];
            float4 w1a = *(const float4*)&WU[buf][P][128 + 8 * w];
            float4 w1b = *(const float4*)&WU[buf][P][128 + 8 * w + 4];
            float4 qa  = *(const float4*)&Qs[buf][P][8 * w];
            float4 qb  = *(const float4*)&Qs[buf][P][8 * w + 4];
            float st0 = stab1(hs[0] + w0a.x * uv0);
            float st1 = stab1(hs[1] + w0a.y * uv0);
            float st2 = stab1(hs[2] + w0a.z * uv0);
            float st3 = stab1(hs[3] + w0a.w * uv0);
            float st4 = stab1(hs[4] + w0b.x * uv0);
            float st5 = stab1(hs[5] + w0b.y * uv0);
            float st6 = stab1(hs[6] + w0b.z * uv0);
            float st7 = stab1(hs[7] + w0b.w * uv0);
            pKH[w][P][lane] =
                  ((w1a.x * st0 + w1a.y * st1) + (w1a.z * st2 + w1a.w * st3))
                + ((w1b.x * st4 + w1b.y * st5) + (w1b.z * st6 + w1b.w * st7));
            pOA[w][P][lane] =
                  ((qa.x * st0 + qa.y * st1) + (qa.z * st2 + qa.w * st3))
                + ((qb.x * st4 + qb.y * st5) + (qb.z * st6 + qb.w * st7));
        }
        stage_write(buf ^ 1);
        __syncthreads();

        if (w < 4) {
            float skh = 0.f, soa = 0.f;
            #pragma unroll
            for (int wv = 0; wv < 8; ++wv) {
                skh += pKH[wv][w][lane];
                soa += pOA[wv][w][lane];
            }
            float uv1 = WU[buf][w][192 + lane] - skh;
            int t = nc * CK + cMain;
            float outv = 0.5f * (Qs[buf][w][lane] * uv1 + soa);
            op[(size_t)t * D + lane] = (t > 0) ? outv : 0.f;
        } else if (w == 4) {
            float skh = 0.f;
            #pragma unroll
            for (int wv = 0; wv < 8; ++wv) skh += pKH[wv][4][lane];
            UV1r[lane] = WU[buf][4][192 + lane] - skh;
        }
        __syncthreads();

        {
            float w0d = WU[buf][4][hd];
            float w1d = WU[buf][4][128 + hd];
            float st2v[8];
            float ssum = 0.f;
            #pragma unroll
            for (int j = 0; j < 8; ++j) {
                float st1 = stab1(hsh[hd][he0 + j] + w0d * UV0[4][he0 + j]);
                float st2 = stab1(st1 + w1d * UV1r[he0 + j]);
                st2v[j] = st2;
                ssum += st2 * st2;
            }
            ssum += __shfl_xor(ssum, 1);
            ssum += __shfl_xor(ssum, 2);
            ssum += __shfl_xor(ssum, 4);
            float xn = __builtin_amdgcn_sqrtf(ssum) + 1e-6f;
            float s2 = 2.f * __builtin_amdgcn_rcpf(xn);
            #pragma unroll
            for (int j = 0; j < 8; ++j) {
                float x  = st2v[j];
                float y  = x * s2;
                float y2 = y * y;
                float e  = __builtin_amdgcn_exp2f(y * (2.3022078f + 0.1029432f * y2));
                float th = (e - 1.f) * __builtin_amdgcn_rcpf(e + 1.f);
                hsh[hd][he0 + j] = 0.25f * x * y * (1.f + th);
            }
        }
        __syncthreads();
    }
}

extern "C" void kernel_launch(void* const* d_in, const int* in_sizes, int n_in,
                              void* d_out, int out_size, void* d_ws, size_t ws_size,
                              hipStream_t stream)
{
    (void)in_sizes; (void)n_in; (void)out_size;
    const float* q    = (const float*)d_in[0];
    const float* k    = (const float*)d_in[1];
    const float* v    = (const float*)d_in[2];
    const float* beta = (const float*)d_in[3];
    float* ws  = (float*)d_ws;
    float* out = (float*)d_out;

    const size_t maxW  = (HGW > GGW) ? HGW : GGW;
    const size_t needF = (YWORDS + GGW + HGW + FLW) * sizeof(float); // ~93.3 MB
    const size_t needA = (YWORDS + maxW) * sizeof(float);            // ~84 MB
    const size_t needB = (YWORDS + GGW) * sizeof(float);             // ~76 MB

    if (ws_size >= needF) {
        float* gG = ws + YWORDS;
        float* hg = gG + GGW;
        unsigned int* flags = (unsigned int*)(hg + HGW);
        hipMemsetAsync(flags, 0, FLW * sizeof(unsigned int), stream);
        la_gram<<<PAIRS * NCH, 256, 0, stream>>>(k, gG);
        la_p1scan<<<PAIRS + PAIRS * NCH * 2, 256, 0, stream>>>(
            k, v, beta, ws, gG, hg, flags);
        la_out<<<PAIRS * NCH, 512, 0, stream>>>(q, ws, hg, out);
    } else if (ws_size >= needA) {
        float* gG = ws + YWORDS;
        float* hg = ws + YWORDS;   // aliases gG (dead before la_scan)
        la_gram<<<PAIRS * NCH, 256, 0, stream>>>(k, gG);
        la_phase1g<<<PAIRS * NCH * 2, 256, 0, stream>>>(k, v, beta, ws, gG);
        la_scan<<<PAIRS, 512, 0, stream>>>(ws, hg);
        la_out<<<PAIRS * NCH, 512, 0, stream>>>(q, ws, hg, out);
    } else if (ws_size >= needB) {
        float* gG = ws + YWORDS;
        la_gram<<<PAIRS * NCH, 256, 0, stream>>>(k, gG);
        la_phase1g<<<PAIRS * NCH * 2, 256, 0, stream>>>(k, v, beta, ws, gG);
        la_phase2<<<PAIRS * NB2, 512, 0, stream>>>(q, ws, out);
    } else {
        la_phase1f<<<PAIRS * NCH * 2, 256, 0, stream>>>(k, v, beta, ws);
        la_phase2<<<PAIRS * NB2, 512, 0, stream>>>(q, ws, out);
    }
}

// Round 20
// 341.880 us; speedup vs baseline: 1.0199x; 1.0199x over previous
//
#include <hip/hip_runtime.h>
#include <math.h>

// LinearAttention (2nd-order derivative-expanded DeltaNet-like), fp32.
// B=2,H=16,S=2048,D=64; n=2; CHUNK=64 -> 128 virtual rows/chunk.
// la_gram:    per-chunk packed Gram -> gG.
// la_phase1g: WY solve, G from global; fully-unrolled g-loop (R16, ~110us).
// la_scanout: FUSED scan+out (512 thr): blocks 0-31 = per-pair h-scan with
//             per-slot release flags; blocks 32+ = out consumers (acquire
//             poll on h[nc], then fully parallel output compute).
// Fallbacks:  phase1g+phase2 (needB), phase1f+phase2 (else).

namespace {
constexpr int PAIRS = 32;   // B*H
constexpr int SLEN  = 2048;
constexpr int D     = 64;
constexpr int CK    = 64;
constexpr int CN    = 128;
constexpr int NCH   = 32;
constexpr int NB2   = 16;   // fallback phase 2
constexpr int NP    = 5;    // fallback phase 2
constexpr size_t YWORDS = (size_t)PAIRS * NCH * CN * CN;   // 16M floats
constexpr int GP = 2145;
constexpr size_t GGW = (size_t)PAIRS * NCH * GP;
constexpr size_t HGW = (size_t)PAIRS * (NCH + 1) * D * D;  // h slots [d][e]
constexpr size_t FLW2 = (size_t)PAIRS * NCH;               // h-ready flags

__device__ __forceinline__ float stab1(float x) {
    float y = __builtin_amdgcn_fmed3f(x, -10000.f, 10000.f);
    return (x != x) ? 0.f : y;
}
__device__ __forceinline__ int kidx(int a, int f4) {
    return a * 68 + 4 * (f4 ^ ((a >> 2) & 3));
}
__device__ __forceinline__ void bar_lds() {
    asm volatile("s_waitcnt lgkmcnt(0)\n\ts_barrier" ::: "memory");
}
} // namespace

// ---------------- la_gram ----------------
__global__ __launch_bounds__(256, 2)
void la_gram(const float* __restrict__ kg, float* __restrict__ gG)
{
    __shared__ float kstf[65 * 68];
    const int blk = blockIdx.x;
    const int p = blk >> 5, nc = blk & 31;
    const int tid = threadIdx.x;
    const int baseT = nc * CK;
    const float* kp = kg + (size_t)p * SLEN * D;

    for (int u = tid; u < 65 * 16; u += 256) {
        int a = u >> 4, f4 = u & 15;
        int src = baseT - 1 + a;
        float4 val = float4{0.f, 0.f, 0.f, 0.f};
        if (src >= 0) val = ((const float4*)(kp + (size_t)src * D))[f4];
        *(float4*)&kstf[kidx(a, f4)] = val;
    }
    __syncthreads();

    float* gps = gG + (size_t)blk * GP;
    for (int tt = tid; tt < 17 * 17; tt += 256) {
        int ta = tt / 17, tb = tt % 17;
        if (tb > ta) continue;
        int a0 = ta * 4, b0 = tb * 4;
        float acc[4][4] = {};
        for (int d4 = 0; d4 < 16; ++d4) {
            float4 av[4], bv[4];
            #pragma unroll
            for (int r = 0; r < 4; ++r) {
                av[r] = *(const float4*)&kstf[kidx(min(a0 + r, 64), d4)];
                bv[r] = *(const float4*)&kstf[kidx(min(b0 + r, 64), d4)];
            }
            #pragma unroll
            for (int r = 0; r < 4; ++r)
                #pragma unroll
                for (int c = 0; c < 4; ++c)
                    acc[r][c] += av[r].x * bv[c].x + av[r].y * bv[c].y
                               + av[r].z * bv[c].z + av[r].w * bv[c].w;
        }
        #pragma unroll
        for (int r = 0; r < 4; ++r)
            #pragma unroll
            for (int c = 0; c < 4; ++c) {
                int a = a0 + r, b = b0 + c;
                if (a <= 64 && b <= a)
                    gps[a * (a + 1) / 2 + b] = acc[r][c];
            }
    }
}

// ---------------- la_phase1g: WY solve, Gram from global, unrolled ----------
__global__ __launch_bounds__(256, 3)
void la_phase1g(const float* __restrict__ kg, const float* __restrict__ vg,
                const float* __restrict__ bg, float* __restrict__ ws,
                const float* __restrict__ gG)
{
    __shared__ float Ysh[CN][64];
    __shared__ float scm[2][CN][8];
    __shared__ float redsh[24][66];
    __shared__ float bq4[CK], bh[CK];

    const int blk  = blockIdx.x;
    const int p    = blk >> 6;
    const int nc   = (blk >> 1) & 31;
    const int half = blk & 1;
    const int tid  = threadIdx.x;
    const int col  = tid & 63;
    const int m    = tid >> 6;
    const int baseT = nc * CK;
    const float* kp = kg + (size_t)p * SLEN * D;
    const float* vp = vg + (size_t)p * SLEN * D;
    const float* bp = bg + (size_t)p * SLEN;
    const float* gps = gG + (size_t)(p * NCH + nc) * GP;

    if (tid < CK) {
        float bv = bp[baseT + tid];
        bq4[tid] = 0.25f * bv;
        bh[tid]  = 0.5f  * bv;
    }
    __syncthreads();

    const float* srcBase = half ? vp : kp;
    for (int u = tid; u < CN * 16; u += 256) {
        int i = u >> 4, f4 = u & 15;
        int ci = i >> 1, si = i & 1;
        float sc = si ? bh[ci] : -bh[ci];
        int srcT = baseT + ci - si;
        float4 val = float4{0.f, 0.f, 0.f, 0.f};
        if (srcT >= 0) val = ((const float4*)(srcBase + (size_t)srcT * D))[f4];
        val.x *= sc; val.y *= sc; val.z *= sc; val.w *= sc;
        *(float4*)&Ysh[i][f4 * 4] = val;
    }
    for (int e = tid; e < 64; e += 256) {
        int j = e >> 3, r = e & 7;
        int ai = (r >> 1) - (r & 1) + 1;
        int aj = (j >> 1) - (j & 1) + 1;
        int amax = max(ai, aj), amin = min(ai, aj);
        float sgn = ((r ^ j) & 1) ? -1.f : 1.f;
        scm[0][j][r] = sgn * bq4[r >> 1] * gps[amax * (amax + 1) / 2 + amin];
    }
    __syncthreads();

    #pragma unroll
    for (int g = 0; g < 16; ++g) {
        const int buf = g & 1;
        float acc[8] = {};
        #pragma unroll
        for (int jj = 0; jj < 2 * g; ++jj) {
            const int j = m + 4 * jj;
            float yv = Ysh[j][col];
            const float4 a03 = *(const float4*)&scm[buf][j][0];
            const float4 a47 = *(const float4*)&scm[buf][j][4];
            acc[0] += a03.x * yv; acc[1] += a03.y * yv;
            acc[2] += a03.z * yv; acc[3] += a03.w * yv;
            acc[4] += a47.x * yv; acc[5] += a47.y * yv;
            acc[6] += a47.z * yv; acc[7] += a47.w * yv;
        }
        if (m > 0) {
            #pragma unroll
            for (int r = 0; r < 8; ++r) redsh[(m - 1) * 8 + r][col] = acc[r];
        }
        bar_lds();
        if (m == 0) {
            if (g > 0) {
                #pragma unroll
                for (int r = 0; r < 8; ++r)
                    acc[r] += redsh[r][col] + redsh[8 + r][col] + redsh[16 + r][col];
            }
            float yn[8];
            #pragma unroll
            for (int r = 0; r < 8; ++r) {
                float val = Ysh[8 * g + r][col] - acc[r];
                #pragma unroll
                for (int rp = 0; rp < 8; ++rp)
                    if (rp < r) val -= scm[buf][8 * g + rp][r] * yn[rp];
                yn[r] = val;
                Ysh[8 * g + r][col] = val;
            }
        } else if (g < 15) {
            const int T = g + 1, bufB = T & 1;
            const int nel = 8 * (8 * T + 8);
            constexpr int MAXIT = 6;          // ceil(8*128/192)
            const int nit = (nel + 191) / 192;
            #pragma unroll
            for (int it = 0; it < MAXIT; ++it) {
                if (it < nit) {
                    const int e = (tid - 64) + 192 * it;
                    if (e < nel) {
                        int j = e >> 3, r = e & 7;
                        int i = 8 * T + r;
                        int ai = (i >> 1) - (i & 1) + 1;
                        int aj = (j >> 1) - (j & 1) + 1;
                        int amax = max(ai, aj), amin = min(ai, aj);
                        float sgn = ((i ^ j) & 1) ? -1.f : 1.f;
                        scm[bufB][j][r] =
                            sgn * bq4[i >> 1] * gps[amax * (amax + 1) / 2 + amin];
                    }
                }
            }
        }
        bar_lds();
    }

    float* gY = ws + (size_t)(p * NCH + nc) * (CN * CN) + half * 64;
    for (int u = tid; u < CN * 16; u += 256) {
        int r = u >> 4, f4 = u & 15;
        *(float4*)&gY[r * CN + f4 * 4] = *(const float4*)&Ysh[r][f4 * 4];
    }
}

// ---------------- la_scanout: fused scan (blocks 0-31) + out (blocks 32+) ---
// 512 threads. Scan = R16 row-mapped version + release flag per h slot.
// Out = R16 la_out + acquire poll on flag[p][nc]. Scan blocks dispatched
// first (blockIdx 0-31) -> always resident -> no deadlock.
__global__ __launch_bounds__(512)
void la_scanout(const float* __restrict__ qg, const float* __restrict__ ws,
                float* __restrict__ hg, float* __restrict__ outg,
                unsigned int* __restrict__ flags)
{
    __shared__ char shm[23808];
    const int blk = blockIdx.x;
    const int tid = threadIdx.x;

    if (blk < PAIRS) {
        // ================= scan (per-pair sequential) =================
        float* w0s = (float*)shm;                        // [64]
        float* u0s = w0s + 64;
        float* w1s = u0s + 64;
        float* u1s = w1s + 64;
        float (*pA)[64] = (float(*)[64])(u1s + 64);      // [8][64]
        float (*pB)[64] = pA + 8;                        // [8][64]
        float (*hsh2)[67] = (float(*)[67])(pB + 8);      // [64][67]

        const int p = blk;
        const int w = tid >> 6, lane = tid & 63;
        const int hd = tid >> 3, he0 = (tid & 7) * 8;
        const float* Yp = ws + (size_t)p * NCH * (CN * CN);
        float* hp = hg + (size_t)p * (NCH + 1) * (D * D);
        unsigned int* fl = flags + (size_t)p * NCH;

        for (int idx = tid; idx < D * D; idx += 512) hp[idx] = 0.f;  // slot 0
        for (int idx = tid; idx < 64 * 67; idx += 512) (&hsh2[0][0])[idx] = 0.f;

        auto stagew = [&](float v) {
            if (tid < 64)       w0s[tid] = v;
            else if (tid < 128) u0s[tid - 64] = v;
            else if (tid < 192) w1s[tid - 128] = v;
            else if (tid < 256) u1s[tid - 192] = v;
        };
        {
            float v = 0.f;
            if (tid < 256) v = Yp[(size_t)(126 + (tid >> 7)) * CN + (tid & 127)];
            stagew(v);
        }
        float hs[8];
        #pragma unroll
        for (int j = 0; j < 8; ++j) hs[j] = 0.f;
        __syncthreads();    // drains slot-0 zero stores (all threads)
        if (tid == 0)
            __hip_atomic_fetch_add(&fl[0], 1u, __ATOMIC_RELEASE,
                                   __HIP_MEMORY_SCOPE_AGENT);

        for (int nc = 0; nc < NCH; ++nc) {
            float pf = 0.f;
            if (nc + 1 < NCH && tid < 256)
                pf = Yp[(size_t)(nc + 1) * (CN * CN)
                        + (size_t)(126 + (tid >> 7)) * CN + (tid & 127)];

            float s = 0.f;
            #pragma unroll
            for (int j = 0; j < 8; ++j) s += w0s[8 * w + j] * hs[j];
            pA[w][lane] = s;
            bar_lds();   // B1

            float sum = 0.f;
            #pragma unroll
            for (int wv = 0; wv < 8; ++wv) sum += pA[wv][lane];
            const float uv0 = u0s[lane] - sum;

            float st1[8];
            float s2 = 0.f;
            #pragma unroll
            for (int j = 0; j < 8; ++j) {
                st1[j] = stab1(hs[j] + w0s[8 * w + j] * uv0);
                s2 += w1s[8 * w + j] * st1[j];
            }
            pB[w][lane] = s2;
            bar_lds();   // B2

            float sum2 = 0.f;
            #pragma unroll
            for (int wv = 0; wv < 8; ++wv) sum2 += pB[wv][lane];
            const float uv1 = u1s[lane] - sum2;
            #pragma unroll
            for (int j = 0; j < 8; ++j)
                hsh2[8 * w + j][lane] = stab1(st1[j] + w1s[8 * w + j] * uv1);
            bar_lds();   // B3

            // row-mapped norm + gelu; store h slot nc+1 ([d][e] layout)
            {
                float st2v[8];
                float ssum = 0.f;
                #pragma unroll
                for (int j = 0; j < 8; ++j) {
                    st2v[j] = hsh2[hd][he0 + j];
                    ssum += st2v[j] * st2v[j];
                }
                ssum += __shfl_xor(ssum, 1);
                ssum += __shfl_xor(ssum, 2);
                ssum += __shfl_xor(ssum, 4);
                float xn = __builtin_amdgcn_sqrtf(ssum) + 1e-6f;
                float sc2 = 2.f * __builtin_amdgcn_rcpf(xn);
                float hn[8];
                #pragma unroll
                for (int j = 0; j < 8; ++j) {
                    float x  = st2v[j];
                    float y  = x * sc2;
                    float y2 = y * y;
                    float e  = __builtin_amdgcn_exp2f(
                                   y * (2.3022078f + 0.1029432f * y2));
                    float th = (e - 1.f) * __builtin_amdgcn_rcpf(e + 1.f);
                    hn[j] = 0.25f * x * y * (1.f + th);
                    hsh2[hd][he0 + j] = hn[j];
                }
                float* ho = hp + (size_t)(nc + 1) * (D * D) + hd * 64 + he0;
                *(float4*)&ho[0] = float4{hn[0], hn[1], hn[2], hn[3]};
                *(float4*)&ho[4] = float4{hn[4], hn[5], hn[6], hn[7]};
            }
            if (nc + 1 < NCH) stagew(pf);
            __syncthreads();   // B4: drains h stores (all threads) + LDS order
            if (tid == 0 && nc + 1 < NCH)
                __hip_atomic_fetch_add(&fl[nc + 1], 1u, __ATOMIC_RELEASE,
                                       __HIP_MEMORY_SCOPE_AGENT);
            #pragma unroll
            for (int j = 0; j < 8; ++j) hs[j] = hsh2[8 * w + j][lane];
        }
        return;
    }

    // ================= out consumer =================
    float* hT = (float*)shm;                     // [64*68]
    float (*wbr)[3][64] = (float(*)[3][64])(hT + 64 * 68);  // [8][3][64]

    const int idx2 = blk - PAIRS;
    const int p = idx2 >> 5, nc = idx2 & 31;
    const int w = tid >> 6, lane = tid & 63;

    const float* Yc = ws + (size_t)(p * NCH + nc) * (CN * CN);
    const float* hp = hg + ((size_t)p * (NCH + 1) + nc) * (D * D);
    const float* qp = qg + (size_t)p * SLEN * D;
    float* op = outg + (size_t)p * SLEN * D;

    if (tid == 0) {
        const unsigned int* fl = flags + (size_t)p * NCH;
        while (__hip_atomic_load(&fl[nc], __ATOMIC_ACQUIRE,
                                 __HIP_MEMORY_SCOPE_AGENT) < 1u)
            __builtin_amdgcn_s_sleep(16);
    }
    __syncthreads();

    for (int idx = tid; idx < D * D; idx += 512) {
        int d = idx >> 6, e = idx & 63;
        hT[e * 68 + d] = hp[idx];
    }
    __syncthreads();

    float4 hr[16];   // h[:, lane] column, static-indexed only
    #pragma unroll
    for (int k = 0; k < 16; ++k)
        hr[k] = *(const float4*)&hT[lane * 68 + 4 * k];

    float w0n, u0n, w1n, u1n, qn;
    {
        const int c = w, t = nc * CK + c;
        w0n = Yc[(size_t)(2 * c) * CN + lane];
        u0n = Yc[(size_t)(2 * c) * CN + 64 + lane];
        w1n = Yc[(size_t)(2 * c + 1) * CN + lane];
        u1n = Yc[(size_t)(2 * c + 1) * CN + 64 + lane];
        qn  = qp[(size_t)((t > 0) ? t - 1 : 0) * D + lane];
    }

    for (int it = 0; it < 8; ++it) {
        const int c = it * 8 + w;
        const int t = nc * CK + c;
        const float w0v = w0n, u0l = u0n, w1v = w1n, u1l = u1n, qv = qn;
        if (it < 7) {
            const int c2 = (it + 1) * 8 + w;
            w0n = Yc[(size_t)(2 * c2) * CN + lane];
            u0n = Yc[(size_t)(2 * c2) * CN + 64 + lane];
            w1n = Yc[(size_t)(2 * c2 + 1) * CN + lane];
            u1n = Yc[(size_t)(2 * c2 + 1) * CN + 64 + lane];
            qn  = qp[(size_t)(nc * CK + c2 - 1) * D + lane];
        }

        wbr[w][0][lane] = w0v;
        wbr[w][1][lane] = w1v;
        wbr[w][2][lane] = qv;

        float uv0 = u0l;
        #pragma unroll
        for (int k = 0; k < 16; ++k) {
            float4 wb = *(const float4*)&wbr[w][0][4 * k];
            uv0 -= (wb.x * hr[k].x + wb.y * hr[k].y)
                 + (wb.z * hr[k].z + wb.w * hr[k].w);
        }
        float kh = 0.f, oa = 0.f;
        #pragma unroll
        for (int k = 0; k < 16; ++k) {
            float4 wb0 = *(const float4*)&wbr[w][0][4 * k];
            float4 wb1 = *(const float4*)&wbr[w][1][4 * k];
            float4 qb  = *(const float4*)&wbr[w][2][4 * k];
            float st0 = stab1(hr[k].x + wb0.x * uv0);
            float st1 = stab1(hr[k].y + wb0.y * uv0);
            float st2 = stab1(hr[k].z + wb0.z * uv0);
            float st3 = stab1(hr[k].w + wb0.w * uv0);
            kh += (wb1.x * st0 + wb1.y * st1) + (wb1.z * st2 + wb1.w * st3);
            oa += (qb.x * st0 + qb.y * st1) + (qb.z * st2 + qb.w * st3);
        }
        float uv1 = u1l - kh;
        float outv = 0.5f * (qv * uv1 + oa);
        op[(size_t)t * D + lane] = (t > 0) ? outv : 0.f;
    }
}

// ---------------- la_phase1f: fallback (Gram in LDS) ----------------
__global__ __launch_bounds__(256, 2)
void la_phase1f(const float* __restrict__ kg, const float* __restrict__ vg,
                const float* __restrict__ bg, float* __restrict__ ws)
{
    __shared__ float Ysh[CN][64];
    __shared__ float Gm[65][66];
    __shared__ char  ureg[17680];
    __shared__ float bq4[CK], bh[CK];

    float* kstf = (float*)ureg;
    float* scm  = (float*)ureg;
    float (*redsh)[66] = (float(*)[66])(ureg + 8192);

    const int blk  = blockIdx.x;
    const int p    = blk >> 6;
    const int nc   = (blk >> 1) & 31;
    const int half = blk & 1;
    const int tid  = threadIdx.x;
    const int baseT = nc * CK;
    const float* kp = kg + (size_t)p * SLEN * D;
    const float* vp = vg + (size_t)p * SLEN * D;
    const float* bp = bg + (size_t)p * SLEN;

    for (int u = tid; u < 65 * 16; u += 256) {
        int a = u >> 4, f4 = u & 15;
        int src = baseT - 1 + a;
        float4 val = float4{0.f, 0.f, 0.f, 0.f};
        if (src >= 0) val = ((const float4*)(kp + (size_t)src * D))[f4];
        *(float4*)&kstf[kidx(a, f4)] = val;
    }
    if (tid < CK) {
        float bv = bp[baseT + tid];
        bq4[tid] = 0.25f * bv;
        bh[tid]  = 0.5f  * bv;
    }
    __syncthreads();

    for (int u = tid; u < CN * 16; u += 256) {
        int i = u >> 4, f4 = u & 15;
        int ci = i >> 1, si = i & 1;
        float sc = si ? bh[ci] : -bh[ci];
        float4 val = float4{0.f, 0.f, 0.f, 0.f};
        if (half == 0) {
            val = *(const float4*)&kstf[kidx(ci - si + 1, f4)];
        } else {
            int srcT = baseT + ci - si;
            if (srcT >= 0) val = ((const float4*)(vp + (size_t)srcT * D))[f4];
        }
        val.x *= sc; val.y *= sc; val.z *= sc; val.w *= sc;
        *(float4*)&Ysh[i][f4 * 4] = val;
    }

    for (int tt = tid; tt < 17 * 17; tt += 256) {
        int ta = tt / 17, tb = tt % 17;
        if (tb > ta) continue;
        int a0 = ta * 4, b0 = tb * 4;
        float acc[4][4] = {};
        for (int d4 = 0; d4 < 16; ++d4) {
            float4 av[4], bv[4];
            #pragma unroll
            for (int r = 0; r < 4; ++r) {
                av[r] = *(const float4*)&kstf[kidx(min(a0 + r, 64), d4)];
                bv[r] = *(const float4*)&kstf[kidx(min(b0 + r, 64), d4)];
            }
            #pragma unroll
            for (int r = 0; r < 4; ++r)
                #pragma unroll
                for (int c = 0; c < 4; ++c)
                    acc[r][c] += av[r].x * bv[c].x + av[r].y * bv[c].y
                               + av[r].z * bv[c].z + av[r].w * bv[c].w;
        }
        #pragma unroll
        for (int r = 0; r < 4; ++r)
            #pragma unroll
            for (int c = 0; c < 4; ++c)
                if (a0 + r <= 64 && b0 + c <= 64) {
                    Gm[a0 + r][b0 + c] = acc[r][c];
                    Gm[b0 + c][a0 + r] = acc[r][c];
                }
    }
    __syncthreads();

    auto stripf = [&](int g, int t0, int tstride) {
        int buf = g & 1;
        int jmax = 8 * g + 8;
        for (int e = t0; e < 8 * jmax; e += tstride) {
            int j = e >> 3, r = e & 7;
            int i = 8 * g + r;
            int ai = (i >> 1) - (i & 1) + 1;
            int aj = (j >> 1) - (j & 1) + 1;
            float sgn = ((i ^ j) & 1) ? -1.f : 1.f;
            scm[(buf * CN + j) * 8 + r] = sgn * bq4[i >> 1] * Gm[ai][aj];
        }
    };

    stripf(0, tid, 256);
    __syncthreads();

    const int col = tid & 63;
    const int m   = tid >> 6;
    for (int g = 0; g < 16; ++g) {
        const int buf = g & 1;
        float acc[8] = {};
        for (int j = m; j < 8 * g; j += 4) {
            float yv = Ysh[j][col];
            const float4 a03 = *(const float4*)&scm[(buf * CN + j) * 8];
            const float4 a47 = *(const float4*)&scm[(buf * CN + j) * 8 + 4];
            acc[0] += a03.x * yv; acc[1] += a03.y * yv;
            acc[2] += a03.z * yv; acc[3] += a03.w * yv;
            acc[4] += a47.x * yv; acc[5] += a47.y * yv;
            acc[6] += a47.z * yv; acc[7] += a47.w * yv;
        }
        if (m > 0) {
            #pragma unroll
            for (int r = 0; r < 8; ++r) redsh[(m - 1) * 8 + r][col] = acc[r];
        }
        __syncthreads();
        if (m == 0) {
            if (g > 0) {
                #pragma unroll
                for (int r = 0; r < 8; ++r)
                    acc[r] += redsh[r][col] + redsh[8 + r][col] + redsh[16 + r][col];
            }
            float yn[8];
            #pragma unroll
            for (int r = 0; r < 8; ++r) {
                float val = Ysh[8 * g + r][col] - acc[r];
                #pragma unroll
                for (int rp = 0; rp < 8; ++rp)
                    if (rp < r) val -= scm[(buf * CN + 8 * g + rp) * 8 + r] * yn[rp];
                yn[r] = val;
                Ysh[8 * g + r][col] = val;
            }
        } else if (g < 15) {
            stripf(g + 1, tid - 64, 192);
        }
        __syncthreads();
    }

    float* gY = ws + (size_t)(p * NCH + nc) * (CN * CN) + half * 64;
    for (int u = tid; u < CN * 16; u += 256) {
        int r = u >> 4, f4 = u & 15;
        *(float4*)&gY[r * CN + f4 * 4] = *(const float4*)&Ysh[r][f4 * 4];
    }
}

// ---------------- la_phase2: fallback monolithic scan (R6 config) --------
__global__ __launch_bounds__(512, 4)
void la_phase2(const float* __restrict__ qg, const float* __restrict__ ws,
               float* __restrict__ outg)
{
    __shared__ float WU[2][NP][256];
    __shared__ float Qs[2][NP][64];
    __shared__ float pR1[8][NP][64];
    __shared__ float pKH[8][NP][64];
    __shared__ float pOA[8][NP][64];
    __shared__ float UV0[NP][64];
    __shared__ float UV1r[64];
    __shared__ float hsh[64][67];

    const int blk  = blockIdx.x;
    const int p    = blk >> 4, nb = blk & 15;
    const int tid  = threadIdx.x;
    const int w    = tid >> 6, lane = tid & 63;
    const int hd   = tid >> 3;
    const int he0  = (tid & 7) * 8;

    const float* qp = qg + (size_t)p * SLEN * D;
    float* op = outg + (size_t)p * SLEN * D;
    const float* wsbase = ws + (size_t)p * NCH * (CN * CN);

    const int cMain = nb * 4 + w;

    float4 wuR = float4{0.f, 0.f, 0.f, 0.f};
    float  qR  = 0.f;

    auto stage_load = [&](int nc) {
        const float* gY = wsbase + (size_t)nc * (CN * CN);
        if (w < 4) {
            wuR = *(const float4*)(gY + (size_t)(2 * cMain) * CN + lane * 4);
            int t = nc * CK + cMain;
            qR = qp[(size_t)((t > 0) ? t - 1 : 0) * D + lane];
        } else if (w == 4) {
            wuR = *(const float4*)(gY + (size_t)126 * CN + lane * 4);
            qR = qp[(size_t)(nc * CK + 62) * D + lane];
        }
    };
    auto stage_write = [&](int buf) {
        if (w < NP) {
            *(float4*)&WU[buf][w][lane * 4] = wuR;
            Qs[buf][w][lane] = qR;
        }
    };

    for (int idx = tid; idx < 64 * 67; idx += 512) (&hsh[0][0])[idx] = 0.f;
    stage_load(0);
    stage_write(0);
    __syncthreads();

    for (int nc = 0; nc < NCH; ++nc) {
        const int buf = nc & 1;
        float hs[8];
        #pragma unroll
        for (int j = 0; j < 8; ++j) hs[j] = hsh[8 * w + j][lane];
        if (nc + 1 < NCH) stage_load(nc + 1);

        #pragma unroll
        for (int P = 0; P < NP; ++P) {
            float4 a = *(const float4*)&WU[buf][P][8 * w];
            float4 b = *(const float4*)&WU[buf][P][8 * w + 4];
            pR1[w][P][lane] =
                  ((a.x * hs[0] + a.y * hs[1]) + (a.z * hs[2] + a.w * hs[3]))
                + ((b.x * hs[4] + b.y * hs[5]) + (b.z * hs[6] + b.w * hs[7]));
        }
        __syncthreads();

        if (w < NP) {
            float s = 0.f;
            #pragma unroll
            for (int wv = 0; wv < 8; ++wv) s += pR1[wv][w][lane];
            UV0[w][lane] = WU[buf][w][64 + lane] - s;
        }
        __syncthreads();

        #pragma unroll
        for (int P = 0; P < NP; ++P) {
            float uv0 = UV0[P][lane];
            float4 w0a = *(const float4*)&WU[buf][P][8 * w];
            float4 w0b = *(const float4*)&WU[buf][P][8 * w + 4];
            float4 w1a = *(const float4*)&WU[buf][P][128 + 8 * w];
            float4 w1b = *(const float4*)&WU[buf][P][128 + 8 * w + 4];
            float4 qa  = *(const float4*)&Qs[buf][P][8 * w];
            float4 qb  = *(const float4*)&Qs[buf][P][8 * w + 4];
            float st0 = stab1(hs[0] + w0a.x * uv0);
            float st1 = stab1(hs[1] + w0a.y * uv0);
            float st2 = stab1(hs[2] + w0a.z * uv0);
            float st3 = stab1(hs[3] + w0a.w * uv0);
            float st4 = stab1(hs[4] + w0b.x * uv0);
            float st5 = stab1(hs[5] + w0b.y * uv0);
            float st6 = stab1(hs[6] + w0b.z * uv0);
            float st7 = stab1(hs[7] + w0b.w * uv0);
            pKH[w][P][lane] =
                  ((w1a.x * st0 + w1a.y * st1) + (w1a.z * st2 + w1a.w * st3))
                + ((w1b.x * st4 + w1b.y * st5) + (w1b.z * st6 + w1b.w * st7));
            pOA[w][P][lane] =
                  ((qa.x * st0 + qa.y * st1) + (qa.z * st2 + qa.w * st3))
                + ((qb.x * st4 + qb.y * st5) + (qb.z * st6 + qb.w * st7));
        }
        stage_write(buf ^ 1);
        __syncthreads();

        if (w < 4) {
            float skh = 0.f, soa = 0.f;
            #pragma unroll
            for (int wv = 0; wv < 8; ++wv) {
                skh += pKH[wv][w][lane];
                soa += pOA[wv][w][lane];
            }
            float uv1 = WU[buf][w][192 + lane] - skh;
            int t = nc * CK + cMain;
            float outv = 0.5f * (Qs[buf][w][lane] * uv1 + soa);
            op[(size_t)t * D + lane] = (t > 0) ? outv : 0.f;
        } else if (w == 4) {
            float skh = 0.f;
            #pragma unroll
            for (int wv = 0; wv < 8; ++wv) skh += pKH[wv][4][lane];
            UV1r[lane] = WU[buf][4][192 + lane] - skh;
        }
        __syncthreads();

        {
            float w0d = WU[buf][4][hd];
            float w1d = WU[buf][4][128 + hd];
            float st2v[8];
            float ssum = 0.f;
            #pragma unroll
            for (int j = 0; j < 8; ++j) {
                float st1 = stab1(hsh[hd][he0 + j] + w0d * UV0[4][he0 + j]);
                float st2 = stab1(st1 + w1d * UV1r[he0 + j]);
                st2v[j] = st2;
                ssum += st2 * st2;
            }
            ssum += __shfl_xor(ssum, 1);
            ssum += __shfl_xor(ssum, 2);
            ssum += __shfl_xor(ssum, 4);
            float xn = __builtin_amdgcn_sqrtf(ssum) + 1e-6f;
            float s2 = 2.f * __builtin_amdgcn_rcpf(xn);
            #pragma unroll
            for (int j = 0; j < 8; ++j) {
                float x  = st2v[j];
                float y  = x * s2;
                float y2 = y * y;
                float e  = __builtin_amdgcn_exp2f(y * (2.3022078f + 0.1029432f * y2));
                float th = (e - 1.f) * __builtin_amdgcn_rcpf(e + 1.f);
                hsh[hd][he0 + j] = 0.25f * x * y * (1.f + th);
            }
        }
        __syncthreads();
    }
}

extern "C" void kernel_launch(void* const* d_in, const int* in_sizes, int n_in,
                              void* d_out, int out_size, void* d_ws, size_t ws_size,
                              hipStream_t stream)
{
    (void)in_sizes; (void)n_in; (void)out_size;
    const float* q    = (const float*)d_in[0];
    const float* k    = (const float*)d_in[1];
    const float* v    = (const float*)d_in[2];
    const float* beta = (const float*)d_in[3];
    float* ws  = (float*)d_ws;
    float* out = (float*)d_out;

    // region2 holds gG then (after phase1g completes) is reused for hg.
    const size_t reg2  = (HGW > GGW) ? HGW : GGW;
    const size_t needF = (YWORDS + reg2 + FLW2) * sizeof(float);  // ~81.6 MB
    const size_t needB = (YWORDS + GGW) * sizeof(float);          // ~76 MB

    if (ws_size >= needF) {
        float* gG = ws + YWORDS;
        float* hg = ws + YWORDS;                   // aliases gG (dead by then)
        unsigned int* flags = (unsigned int*)(ws + YWORDS + reg2);
        hipMemsetAsync(flags, 0, FLW2 * sizeof(unsigned int), stream);
        la_gram<<<PAIRS * NCH, 256, 0, stream>>>(k, gG);
        la_phase1g<<<PAIRS * NCH * 2, 256, 0, stream>>>(k, v, beta, ws, gG);
        la_scanout<<<PAIRS + PAIRS * NCH, 512, 0, stream>>>(q, ws, hg, out, flags);
    } else if (ws_size >= needB) {
        float* gG = ws + YWORDS;
        la_gram<<<PAIRS * NCH, 256, 0, stream>>>(k, gG);
        la_phase1g<<<PAIRS * NCH * 2, 256, 0, stream>>>(k, v, beta, ws, gG);
        la_phase2<<<PAIRS * NB2, 512, 0, stream>>>(q, ws, out);
    } else {
        la_phase1f<<<PAIRS * NCH * 2, 256, 0, stream>>>(k, v, beta, ws);
        la_phase2<<<PAIRS * NB2, 512, 0, stream>>>(q, ws, out);
    }
}

// Round 21
// 260.458 us; speedup vs baseline: 1.3387x; 1.3126x over previous
//
#include <hip/hip_runtime.h>
#include <math.h>

// LinearAttention (2nd-order derivative-expanded DeltaNet-like), fp32.
// B=2,H=16,S=2048,D=64; n=2; CHUNK=64 real tokens -> 128 virtual rows/chunk.
// la_gram:    per-chunk packed Gram G (65x65 lower-tri) -> d_ws after Y.
// la_phase1g: WY solve, G from global; fully-unrolled g-loop (~110us).
// la_scan:    sequential h-state scan; row-mapped norm (3-shfl), standalone
//             (fusion attempts R17-R19 all regressed: rate/spill/contention).
// la_out:     all outputs, fully parallel; no register cap (spill-free).
// Fallbacks (smaller ws): la_phase1f and monolithic la_phase2 (R6 config).

namespace {
constexpr int PAIRS = 32;   // B*H
constexpr int SLEN  = 2048;
constexpr int D     = 64;
constexpr int CK    = 64;   // real tokens per chunk
constexpr int CN    = 128;  // virtual rows per chunk
constexpr int NCH   = 32;   // chunks
constexpr int NB2   = 16;   // blocks per pair in fallback phase 2
constexpr int NP    = 5;    // positions per fallback phase-2 block
constexpr size_t YWORDS = (size_t)PAIRS * NCH * CN * CN;   // 16M floats
constexpr int GP = 2145;    // packed 65x65 lower-tri floats per chunk
constexpr size_t GGW = (size_t)PAIRS * NCH * GP;
constexpr size_t HGW = (size_t)PAIRS * (NCH + 1) * D * D;  // 33 slots/pair

// _stab: nan->0, clip to +-1e4. Clip is load-bearing (values genuinely overflow);
// NaN check must be explicit (med3/min/max drop NaN to a bound).
__device__ __forceinline__ float stab1(float x) {
    float y = __builtin_amdgcn_fmed3f(x, -10000.f, 10000.f);
    return (x != x) ? 0.f : y;
}

// swizzled float-index into kst: row a, float4 index f4 (0..15), stride 68 floats.
__device__ __forceinline__ int kidx(int a, int f4) {
    return a * 68 + 4 * (f4 ^ ((a >> 2) & 3));
}

// barrier ordering LDS only (skips __syncthreads' vmcnt(0) drain so in-flight
// global loads/stores can span barriers; data deps still get vmcnt waits).
__device__ __forceinline__ void bar_lds() {
    asm volatile("s_waitcnt lgkmcnt(0)\n\ts_barrier" ::: "memory");
}
} // namespace

// ---------------- la_gram: packed per-chunk Gram -> global ----------------
__global__ __launch_bounds__(256, 2)
void la_gram(const float* __restrict__ kg, float* __restrict__ gG)
{
    __shared__ float kstf[65 * 68];
    const int blk = blockIdx.x;
    const int p = blk >> 5, nc = blk & 31;
    const int tid = threadIdx.x;
    const int baseT = nc * CK;
    const float* kp = kg + (size_t)p * SLEN * D;

    for (int u = tid; u < 65 * 16; u += 256) {
        int a = u >> 4, f4 = u & 15;
        int src = baseT - 1 + a;
        float4 val = float4{0.f, 0.f, 0.f, 0.f};
        if (src >= 0) val = ((const float4*)(kp + (size_t)src * D))[f4];
        *(float4*)&kstf[kidx(a, f4)] = val;
    }
    __syncthreads();

    float* gps = gG + (size_t)blk * GP;
    for (int tt = tid; tt < 17 * 17; tt += 256) {
        int ta = tt / 17, tb = tt % 17;
        if (tb > ta) continue;
        int a0 = ta * 4, b0 = tb * 4;
        float acc[4][4] = {};
        for (int d4 = 0; d4 < 16; ++d4) {
            float4 av[4], bv[4];
            #pragma unroll
            for (int r = 0; r < 4; ++r) {
                av[r] = *(const float4*)&kstf[kidx(min(a0 + r, 64), d4)];
                bv[r] = *(const float4*)&kstf[kidx(min(b0 + r, 64), d4)];
            }
            #pragma unroll
            for (int r = 0; r < 4; ++r)
                #pragma unroll
                for (int c = 0; c < 4; ++c)
                    acc[r][c] += av[r].x * bv[c].x + av[r].y * bv[c].y
                               + av[r].z * bv[c].z + av[r].w * bv[c].w;
        }
        #pragma unroll
        for (int r = 0; r < 4; ++r)
            #pragma unroll
            for (int c = 0; c < 4; ++c) {
                int a = a0 + r, b = b0 + c;
                if (a <= 64 && b <= a)
                    gps[a * (a + 1) / 2 + b] = acc[r][c];
            }
    }
}

// ---------------- la_phase1g: WY solve, Gram from global, unrolled ----------
__global__ __launch_bounds__(256, 3)
void la_phase1g(const float* __restrict__ kg, const float* __restrict__ vg,
                const float* __restrict__ bg, float* __restrict__ ws,
                const float* __restrict__ gG)
{
    __shared__ float Ysh[CN][64];
    __shared__ float scm[2][CN][8];
    __shared__ float redsh[24][66];
    __shared__ float bq4[CK], bh[CK];

    const int blk  = blockIdx.x;
    const int p    = blk >> 6;
    const int nc   = (blk >> 1) & 31;
    const int half = blk & 1;
    const int tid  = threadIdx.x;
    const int col  = tid & 63;
    const int m    = tid >> 6;
    const int baseT = nc * CK;
    const float* kp = kg + (size_t)p * SLEN * D;
    const float* vp = vg + (size_t)p * SLEN * D;
    const float* bp = bg + (size_t)p * SLEN;
    const float* gps = gG + (size_t)(p * NCH + nc) * GP;

    if (tid < CK) {
        float bv = bp[baseT + tid];
        bq4[tid] = 0.25f * bv;
        bh[tid]  = 0.5f  * bv;
    }
    __syncthreads();

    const float* srcBase = half ? vp : kp;
    for (int u = tid; u < CN * 16; u += 256) {
        int i = u >> 4, f4 = u & 15;
        int ci = i >> 1, si = i & 1;
        float sc = si ? bh[ci] : -bh[ci];
        int srcT = baseT + ci - si;
        float4 val = float4{0.f, 0.f, 0.f, 0.f};
        if (srcT >= 0) val = ((const float4*)(srcBase + (size_t)srcT * D))[f4];
        val.x *= sc; val.y *= sc; val.z *= sc; val.w *= sc;
        *(float4*)&Ysh[i][f4 * 4] = val;
    }
    for (int e = tid; e < 64; e += 256) {
        int j = e >> 3, r = e & 7;
        int ai = (r >> 1) - (r & 1) + 1;
        int aj = (j >> 1) - (j & 1) + 1;
        int amax = max(ai, aj), amin = min(ai, aj);
        float sgn = ((r ^ j) & 1) ? -1.f : 1.f;
        scm[0][j][r] = sgn * bq4[r >> 1] * gps[amax * (amax + 1) / 2 + amin];
    }
    __syncthreads();

    #pragma unroll
    for (int g = 0; g < 16; ++g) {
        const int buf = g & 1;
        float acc[8] = {};
        #pragma unroll
        for (int jj = 0; jj < 2 * g; ++jj) {
            const int j = m + 4 * jj;
            float yv = Ysh[j][col];
            const float4 a03 = *(const float4*)&scm[buf][j][0];
            const float4 a47 = *(const float4*)&scm[buf][j][4];
            acc[0] += a03.x * yv; acc[1] += a03.y * yv;
            acc[2] += a03.z * yv; acc[3] += a03.w * yv;
            acc[4] += a47.x * yv; acc[5] += a47.y * yv;
            acc[6] += a47.z * yv; acc[7] += a47.w * yv;
        }
        if (m > 0) {
            #pragma unroll
            for (int r = 0; r < 8; ++r) redsh[(m - 1) * 8 + r][col] = acc[r];
        }
        bar_lds();
        if (m == 0) {
            if (g > 0) {
                #pragma unroll
                for (int r = 0; r < 8; ++r)
                    acc[r] += redsh[r][col] + redsh[8 + r][col] + redsh[16 + r][col];
            }
            float yn[8];
            #pragma unroll
            for (int r = 0; r < 8; ++r) {
                float val = Ysh[8 * g + r][col] - acc[r];
                #pragma unroll
                for (int rp = 0; rp < 8; ++rp)
                    if (rp < r) val -= scm[buf][8 * g + rp][r] * yn[rp];
                yn[r] = val;
                Ysh[8 * g + r][col] = val;
            }
        } else if (g < 15) {
            const int T = g + 1, bufB = T & 1;
            const int nel = 8 * (8 * T + 8);
            constexpr int MAXIT = 6;          // ceil(8*128/192)
            const int nit = (nel + 191) / 192;
            #pragma unroll
            for (int it = 0; it < MAXIT; ++it) {
                if (it < nit) {
                    const int e = (tid - 64) + 192 * it;
                    if (e < nel) {
                        int j = e >> 3, r = e & 7;
                        int i = 8 * T + r;
                        int ai = (i >> 1) - (i & 1) + 1;
                        int aj = (j >> 1) - (j & 1) + 1;
                        int amax = max(ai, aj), amin = min(ai, aj);
                        float sgn = ((i ^ j) & 1) ? -1.f : 1.f;
                        scm[bufB][j][r] =
                            sgn * bq4[i >> 1] * gps[amax * (amax + 1) / 2 + amin];
                    }
                }
            }
        }
        bar_lds();
    }

    float* gY = ws + (size_t)(p * NCH + nc) * (CN * CN) + half * 64;
    for (int u = tid; u < CN * 16; u += 256) {
        int r = u >> 4, f4 = u & 15;
        *(float4*)&gY[r * CN + f4 * 4] = *(const float4*)&Ysh[r][f4 * 4];
    }
}

// ---------------- la_scan: sequential h-state scan (row-mapped) ---------
// grid = PAIRS (32 blocks, 1/pair), block = 512 (8 waves). Wave w owns h rows
// [8w,8w+8) (col e=lane) in registers between chunks; norm/gelu row-mapped
// via hsh2 with 3-shfl reduce. lgkmcnt-only barriers.
__global__ __launch_bounds__(512, 1)
void la_scan(const float* __restrict__ ws, float* __restrict__ hg)
{
    __shared__ float w0s[64], u0s[64], w1s[64], u1s[64];
    __shared__ float pA[8][64], pB[8][64];
    __shared__ float hsh2[64][67];

    const int p = blockIdx.x;
    const int tid = threadIdx.x;
    const int w = tid >> 6, lane = tid & 63;
    const int hd = tid >> 3, he0 = (tid & 7) * 8;
    const float* Yp = ws + (size_t)p * NCH * (CN * CN);
    float* hp = hg + (size_t)p * (NCH + 1) * (D * D);

    for (int idx = tid; idx < D * D; idx += 512) hp[idx] = 0.f;   // h_in[0] = 0
    for (int idx = tid; idx < 64 * 67; idx += 512) (&hsh2[0][0])[idx] = 0.f;

    auto stagew = [&](float v) {
        if (tid < 64)       w0s[tid] = v;
        else if (tid < 128) u0s[tid - 64] = v;
        else if (tid < 192) w1s[tid - 128] = v;
        else if (tid < 256) u1s[tid - 192] = v;
    };
    {
        float v = 0.f;
        if (tid < 256) v = Yp[(size_t)(126 + (tid >> 7)) * CN + (tid & 127)];
        stagew(v);
    }
    float hs[8];
    #pragma unroll
    for (int j = 0; j < 8; ++j) hs[j] = 0.f;
    __syncthreads();

    for (int nc = 0; nc < NCH; ++nc) {
        float pf = 0.f;
        if (nc + 1 < NCH && tid < 256)
            pf = Yp[(size_t)(nc + 1) * (CN * CN)
                    + (size_t)(126 + (tid >> 7)) * CN + (tid & 127)];

        // R1: kh0 partial over d-slice
        float s = 0.f;
        #pragma unroll
        for (int j = 0; j < 8; ++j) s += w0s[8 * w + j] * hs[j];
        pA[w][lane] = s;
        bar_lds();   // B1

        float sum = 0.f;
        #pragma unroll
        for (int wv = 0; wv < 8; ++wv) sum += pA[wv][lane];
        const float uv0 = u0s[lane] - sum;

        float st1[8];
        float s2 = 0.f;
        #pragma unroll
        for (int j = 0; j < 8; ++j) {
            st1[j] = stab1(hs[j] + w0s[8 * w + j] * uv0);
            s2 += w1s[8 * w + j] * st1[j];
        }
        pB[w][lane] = s2;
        bar_lds();   // B2

        float sum2 = 0.f;
        #pragma unroll
        for (int wv = 0; wv < 8; ++wv) sum2 += pB[wv][lane];
        const float uv1 = u1s[lane] - sum2;
        #pragma unroll
        for (int j = 0; j < 8; ++j)
            hsh2[8 * w + j][lane] = stab1(st1[j] + w1s[8 * w + j] * uv1);
        bar_lds();   // B3

        // row-mapped norm + gelu; store h_in[nc+1]
        {
            float st2v[8];
            float ssum = 0.f;
            #pragma unroll
            for (int j = 0; j < 8; ++j) {
                st2v[j] = hsh2[hd][he0 + j];
                ssum += st2v[j] * st2v[j];
            }
            ssum += __shfl_xor(ssum, 1);
            ssum += __shfl_xor(ssum, 2);
            ssum += __shfl_xor(ssum, 4);
            float xn = __builtin_amdgcn_sqrtf(ssum) + 1e-6f;
            float sc2 = 2.f * __builtin_amdgcn_rcpf(xn);
            float hn[8];
            #pragma unroll
            for (int j = 0; j < 8; ++j) {
                float x  = st2v[j];
                float y  = x * sc2;
                float y2 = y * y;
                float e  = __builtin_amdgcn_exp2f(y * (2.3022078f + 0.1029432f * y2));
                float th = (e - 1.f) * __builtin_amdgcn_rcpf(e + 1.f);
                hn[j] = 0.25f * x * y * (1.f + th);
                hsh2[hd][he0 + j] = hn[j];
            }
            float* ho = hp + (size_t)(nc + 1) * (D * D) + hd * 64 + he0;
            *(float4*)&ho[0] = float4{hn[0], hn[1], hn[2], hn[3]};
            *(float4*)&ho[4] = float4{hn[4], hn[5], hn[6], hn[7]};
        }
        if (nc + 1 < NCH) stagew(pf);
        bar_lds();   // B4
        #pragma unroll
        for (int j = 0; j < 8; ++j) hs[j] = hsh2[8 * w + j][lane];
    }
}

// ---------------- la_out: all outputs, fully parallel ----------------
// grid = PAIRS*NCH (1024), block = 512 (8 waves). NO min-waves bound: hr[16]
// (64 VGPR) must stay in registers (bounds(512,4) spilled it -> scratch, R14).
__global__ __launch_bounds__(512)
void la_out(const float* __restrict__ qg, const float* __restrict__ ws,
            const float* __restrict__ hg, float* __restrict__ outg)
{
    __shared__ float hT[64 * 68];      // hT[e][d], stride 68
    __shared__ float wbr[8][3][64];    // per-wave {w0, w1, qrow}

    const int blk = blockIdx.x;
    const int p = blk >> 5, nc = blk & 31;
    const int tid = threadIdx.x;
    const int w = tid >> 6, lane = tid & 63;

    const float* Yc = ws + (size_t)(p * NCH + nc) * (CN * CN);
    const float* hp = hg + ((size_t)p * (NCH + 1) + nc) * (D * D);
    const float* qp = qg + (size_t)p * SLEN * D;
    float* op = outg + (size_t)p * SLEN * D;

    for (int idx = tid; idx < D * D; idx += 512) {
        int d = idx >> 6, e = idx & 63;
        hT[e * 68 + d] = hp[idx];
    }
    __syncthreads();

    float4 hr[16];                      // h[:, lane] column, static-indexed only
    #pragma unroll
    for (int k = 0; k < 16; ++k)
        hr[k] = *(const float4*)&hT[lane * 68 + 4 * k];

    float w0n, u0n, w1n, u1n, qn;
    {
        const int c = w, t = nc * CK + c;
        w0n = Yc[(size_t)(2 * c) * CN + lane];
        u0n = Yc[(size_t)(2 * c) * CN + 64 + lane];
        w1n = Yc[(size_t)(2 * c + 1) * CN + lane];
        u1n = Yc[(size_t)(2 * c + 1) * CN + 64 + lane];
        qn  = qp[(size_t)((t > 0) ? t - 1 : 0) * D + lane];
    }

    for (int it = 0; it < 8; ++it) {
        const int c = it * 8 + w;
        const int t = nc * CK + c;
        const float w0v = w0n, u0l = u0n, w1v = w1n, u1l = u1n, qv = qn;
        if (it < 7) {
            const int c2 = (it + 1) * 8 + w;
            w0n = Yc[(size_t)(2 * c2) * CN + lane];
            u0n = Yc[(size_t)(2 * c2) * CN + 64 + lane];
            w1n = Yc[(size_t)(2 * c2 + 1) * CN + lane];
            u1n = Yc[(size_t)(2 * c2 + 1) * CN + 64 + lane];
            qn  = qp[(size_t)(nc * CK + c2 - 1) * D + lane];
        }

        wbr[w][0][lane] = w0v;
        wbr[w][1][lane] = w1v;
        wbr[w][2][lane] = qv;

        float uv0 = u0l;
        #pragma unroll
        for (int k = 0; k < 16; ++k) {
            float4 wb = *(const float4*)&wbr[w][0][4 * k];
            uv0 -= (wb.x * hr[k].x + wb.y * hr[k].y)
                 + (wb.z * hr[k].z + wb.w * hr[k].w);
        }
        float kh = 0.f, oa = 0.f;
        #pragma unroll
        for (int k = 0; k < 16; ++k) {
            float4 wb0 = *(const float4*)&wbr[w][0][4 * k];
            float4 wb1 = *(const float4*)&wbr[w][1][4 * k];
            float4 qb  = *(const float4*)&wbr[w][2][4 * k];
            float st0 = stab1(hr[k].x + wb0.x * uv0);
            float st1 = stab1(hr[k].y + wb0.y * uv0);
            float st2 = stab1(hr[k].z + wb0.z * uv0);
            float st3 = stab1(hr[k].w + wb0.w * uv0);
            kh += (wb1.x * st0 + wb1.y * st1) + (wb1.z * st2 + wb1.w * st3);
            oa += (qb.x * st0 + qb.y * st1) + (qb.z * st2 + qb.w * st3);
        }
        float uv1 = u1l - kh;
        float outv = 0.5f * (qv * uv1 + oa);
        op[(size_t)t * D + lane] = (t > 0) ? outv : 0.f;
    }
}

// ---------------- la_phase1f: fallback (Gram in LDS) ----------------
__global__ __launch_bounds__(256, 2)
void la_phase1f(const float* __restrict__ kg, const float* __restrict__ vg,
                const float* __restrict__ bg, float* __restrict__ ws)
{
    __shared__ float Ysh[CN][64];
    __shared__ float Gm[65][66];
    __shared__ char  ureg[17680];
    __shared__ float bq4[CK], bh[CK];

    float* kstf = (float*)ureg;
    float* scm  = (float*)ureg;
    float (*redsh)[66] = (float(*)[66])(ureg + 8192);

    const int blk  = blockIdx.x;
    const int p    = blk >> 6;
    const int nc   = (blk >> 1) & 31;
    const int half = blk & 1;
    const int tid  = threadIdx.x;
    const int baseT = nc * CK;
    const float* kp = kg + (size_t)p * SLEN * D;
    const float* vp = vg + (size_t)p * SLEN * D;
    const float* bp = bg + (size_t)p * SLEN;

    for (int u = tid; u < 65 * 16; u += 256) {
        int a = u >> 4, f4 = u & 15;
        int src = baseT - 1 + a;
        float4 val = float4{0.f, 0.f, 0.f, 0.f};
        if (src >= 0) val = ((const float4*)(kp + (size_t)src * D))[f4];
        *(float4*)&kstf[kidx(a, f4)] = val;
    }
    if (tid < CK) {
        float bv = bp[baseT + tid];
        bq4[tid] = 0.25f * bv;
        bh[tid]  = 0.5f  * bv;
    }
    __syncthreads();

    for (int u = tid; u < CN * 16; u += 256) {
        int i = u >> 4, f4 = u & 15;
        int ci = i >> 1, si = i & 1;
        float sc = si ? bh[ci] : -bh[ci];
        float4 val = float4{0.f, 0.f, 0.f, 0.f};
        if (half == 0) {
            val = *(const float4*)&kstf[kidx(ci - si + 1, f4)];
        } else {
            int srcT = baseT + ci - si;
            if (srcT >= 0) val = ((const float4*)(vp + (size_t)srcT * D))[f4];
        }
        val.x *= sc; val.y *= sc; val.z *= sc; val.w *= sc;
        *(float4*)&Ysh[i][f4 * 4] = val;
    }

    for (int tt = tid; tt < 17 * 17; tt += 256) {
        int ta = tt / 17, tb = tt % 17;
        if (tb > ta) continue;
        int a0 = ta * 4, b0 = tb * 4;
        float acc[4][4] = {};
        for (int d4 = 0; d4 < 16; ++d4) {
            float4 av[4], bv[4];
            #pragma unroll
            for (int r = 0; r < 4; ++r) {
                av[r] = *(const float4*)&kstf[kidx(min(a0 + r, 64), d4)];
                bv[r] = *(const float4*)&kstf[kidx(min(b0 + r, 64), d4)];
            }
            #pragma unroll
            for (int r = 0; r < 4; ++r)
                #pragma unroll
                for (int c = 0; c < 4; ++c)
                    acc[r][c] += av[r].x * bv[c].x + av[r].y * bv[c].y
                               + av[r].z * bv[c].z + av[r].w * bv[c].w;
        }
        #pragma unroll
        for (int r = 0; r < 4; ++r)
            #pragma unroll
            for (int c = 0; c < 4; ++c)
                if (a0 + r <= 64 && b0 + c <= 64) {
                    Gm[a0 + r][b0 + c] = acc[r][c];
                    Gm[b0 + c][a0 + r] = acc[r][c];
                }
    }
    __syncthreads();

    auto stripf = [&](int g, int t0, int tstride) {
        int buf = g & 1;
        int jmax = 8 * g + 8;
        for (int e = t0; e < 8 * jmax; e += tstride) {
            int j = e >> 3, r = e & 7;
            int i = 8 * g + r;
            int ai = (i >> 1) - (i & 1) + 1;
            int aj = (j >> 1) - (j & 1) + 1;
            float sgn = ((i ^ j) & 1) ? -1.f : 1.f;
            scm[(buf * CN + j) * 8 + r] = sgn * bq4[i >> 1] * Gm[ai][aj];
        }
    };

    stripf(0, tid, 256);
    __syncthreads();

    const int col = tid & 63;
    const int m   = tid >> 6;
    for (int g = 0; g < 16; ++g) {
        const int buf = g & 1;
        float acc[8] = {};
        for (int j = m; j < 8 * g; j += 4) {
            float yv = Ysh[j][col];
            const float4 a03 = *(const float4*)&scm[(buf * CN + j) * 8];
            const float4 a47 = *(const float4*)&scm[(buf * CN + j) * 8 + 4];
            acc[0] += a03.x * yv; acc[1] += a03.y * yv;
            acc[2] += a03.z * yv; acc[3] += a03.w * yv;
            acc[4] += a47.x * yv; acc[5] += a47.y * yv;
            acc[6] += a47.z * yv; acc[7] += a47.w * yv;
        }
        if (m > 0) {
            #pragma unroll
            for (int r = 0; r < 8; ++r) redsh[(m - 1) * 8 + r][col] = acc[r];
        }
        __syncthreads();
        if (m == 0) {
            if (g > 0) {
                #pragma unroll
                for (int r = 0; r < 8; ++r)
                    acc[r] += redsh[r][col] + redsh[8 + r][col] + redsh[16 + r][col];
            }
            float yn[8];
            #pragma unroll
            for (int r = 0; r < 8; ++r) {
                float val = Ysh[8 * g + r][col] - acc[r];
                #pragma unroll
                for (int rp = 0; rp < 8; ++rp)
                    if (rp < r) val -= scm[(buf * CN + 8 * g + rp) * 8 + r] * yn[rp];
                yn[r] = val;
                Ysh[8 * g + r][col] = val;
            }
        } else if (g < 15) {
            stripf(g + 1, tid - 64, 192);
        }
        __syncthreads();
    }

    float* gY = ws + (size_t)(p * NCH + nc) * (CN * CN) + half * 64;
    for (int u = tid; u < CN * 16; u += 256) {
        int r = u >> 4, f4 = u & 15;
        *(float4*)&gY[r * CN + f4 * 4] = *(const float4*)&Ysh[r][f4 * 4];
    }
}

// ---------------- la_phase2: fallback monolithic scan (R6 config) --------
__global__ __launch_bounds__(512, 4)
void la_phase2(const float* __restrict__ qg, const float* __restrict__ ws,
               float* __restrict__ outg)
{
    __shared__ float WU[2][NP][256];
    __shared__ float Qs[2][NP][64];
    __shared__ float pR1[8][NP][64];
    __shared__ float pKH[8][NP][64];
    __shared__ float pOA[8][NP][64];
    __shared__ float UV0[NP][64];
    __shared__ float UV1r[64];
    __shared__ float hsh[64][67];

    const int blk  = blockIdx.x;
    const int p    = blk >> 4, nb = blk & 15;
    const int tid  = threadIdx.x;
    const int w    = tid >> 6, lane = tid & 63;
    const int hd   = tid >> 3;
    const int he0  = (tid & 7) * 8;

    const float* qp = qg + (size_t)p * SLEN * D;
    float* op = outg + (size_t)p * SLEN * D;
    const float* wsbase = ws + (size_t)p * NCH * (CN * CN);

    const int cMain = nb * 4 + w;

    float4 wuR = float4{0.f, 0.f, 0.f, 0.f};
    float  qR  = 0.f;

    auto stage_load = [&](int nc) {
        const float* gY = wsbase + (size_t)nc * (CN * CN);
        if (w < 4) {
            wuR = *(const float4*)(gY + (size_t)(2 * cMain) * CN + lane * 4);
            int t = nc * CK + cMain;
            qR = qp[(size_t)((t > 0) ? t - 1 : 0) * D + lane];
        } else if (w == 4) {
            wuR = *(const float4*)(gY + (size_t)126 * CN + lane * 4);
            qR = qp[(size_t)(nc * CK + 62) * D + lane];
        }
    };
    auto stage_write = [&](int buf) {
        if (w < NP) {
            *(float4*)&WU[buf][w][lane * 4] = wuR;
            Qs[buf][w][lane] = qR;
        }
    };

    for (int idx = tid; idx < 64 * 67; idx += 512) (&hsh[0][0])[idx] = 0.f;
    stage_load(0);
    stage_write(0);
    __syncthreads();

    for (int nc = 0; nc < NCH; ++nc) {
        const int buf = nc & 1;
        float hs[8];
        #pragma unroll
        for (int j = 0; j < 8; ++j) hs[j] = hsh[8 * w + j][lane];
        if (nc + 1 < NCH) stage_load(nc + 1);

        #pragma unroll
        for (int P = 0; P < NP; ++P) {
            float4 a = *(const float4*)&WU[buf][P][8 * w];
            float4 b = *(const float4*)&WU[buf][P][8 * w + 4];
            pR1[w][P][lane] =
                  ((a.x * hs[0] + a.y * hs[1]) + (a.z * hs[2] + a.w * hs[3]))
                + ((b.x * hs[4] + b.y * hs[5]) + (b.z * hs[6] + b.w * hs[7]));
        }
        __syncthreads();

        if (w < NP) {
            float s = 0.f;
            #pragma unroll
            for (int wv = 0; wv < 8; ++wv) s += pR1[wv][w][lane];
            UV0[w][lane] = WU[buf][w][64 + lane] - s;
        }
        __syncthreads();

        #pragma unroll
        for (int P = 0; P < NP; ++P) {
            float uv0 = UV0[P][lane];
            float4 w0a = *(const float4*)&WU[buf][P][8 * w];
            float4 w0b = *(const float4*)&WU[buf][P][8 * w + 4];
            float4 w1a = *(const float4*)&WU[buf][P][128 + 8 * w];
            float4 w1b = *(const float4*)&WU[buf][P][128 + 8 * w + 4];
            float4 qa  = *(const float4*)&Qs[buf][P][8 * w];
            float4 qb  = *(const float4*)&Qs[buf][P][8 * w + 4];
            float st0 = stab1(hs[0] + w0a.x * uv0);
            float st1 = stab1(hs[1] + w0a.y * uv0);
            float st2 = stab1(hs[2] + w0a.z * uv0);
            float st3 = stab1(hs[3] + w0a.w * uv0);
            float st4 = stab1(hs[4] + w0b.x * uv0);
            float st5 = stab1(hs[5] + w0b.y * uv0);
            float st6 = stab1(hs[6] + w0b.z * uv0);
            float st7 = stab1(hs[7] + w0b.w * uv0);
            pKH[w][P][lane] =
                  ((w1a.x * st0 + w1a.y * st1) + (w1a.z * st2 + w1a.w * st3))
                + ((w1b.x * st4 + w1b.y * st5) + (w1b.z * st6 + w1b.w * st7));
            pOA[w][P][lane] =
                  ((qa.x * st0 + qa.y * st1) + (qa.z * st2 + qa.w * st3))
                + ((qb.x * st4 + qb.y * st5) + (qb.z * st6 + qb.w * st7));
        }
        stage_write(buf ^ 1);
        __syncthreads();

        if (w < 4) {
            float skh = 0.f, soa = 0.f;
            #pragma unroll
            for (int wv = 0; wv < 8; ++wv) {
                skh += pKH[wv][w][lane];
                soa += pOA[wv][w][lane];
            }
            float uv1 = WU[buf][w][192 + lane] - skh;
            int t = nc * CK + cMain;
            float outv = 0.5f * (Qs[buf][w][lane] * uv1 + soa);
            op[(size_t)t * D + lane] = (t > 0) ? outv : 0.f;
        } else if (w == 4) {
            float skh = 0.f;
            #pragma unroll
            for (int wv = 0; wv < 8; ++wv) skh += pKH[wv][4][lane];
            UV1r[lane] = WU[buf][4][192 + lane] - skh;
        }
        __syncthreads();

        {
            float w0d = WU[buf][4][hd];
            float w1d = WU[buf][4][128 + hd];
            float st2v[8];
            float ssum = 0.f;
            #pragma unroll
            for (int j = 0; j < 8; ++j) {
                float st1 = stab1(hsh[hd][he0 + j] + w0d * UV0[4][he0 + j]);
                float st2 = stab1(st1 + w1d * UV1r[he0 + j]);
                st2v[j] = st2;
                ssum += st2 * st2;
            }
            ssum += __shfl_xor(ssum, 1);
            ssum += __shfl_xor(ssum, 2);
            ssum += __shfl_xor(ssum, 4);
            float xn = __builtin_amdgcn_sqrtf(ssum) + 1e-6f;
            float s2 = 2.f * __builtin_amdgcn_rcpf(xn);
            #pragma unroll
            for (int j = 0; j < 8; ++j) {
                float x  = st2v[j];
                float y  = x * s2;
                float y2 = y * y;
                float e  = __builtin_amdgcn_exp2f(y * (2.3022078f + 0.1029432f * y2));
                float th = (e - 1.f) * __builtin_amdgcn_rcpf(e + 1.f);
                hsh[hd][he0 + j] = 0.25f * x * y * (1.f + th);
            }
        }
        __syncthreads();
    }
}

extern "C" void kernel_launch(void* const* d_in, const int* in_sizes, int n_in,
                              void* d_out, int out_size, void* d_ws, size_t ws_size,
                              hipStream_t stream)
{
    (void)in_sizes; (void)n_in; (void)out_size;
    const float* q    = (const float*)d_in[0];
    const float* k    = (const float*)d_in[1];
    const float* v    = (const float*)d_in[2];
    const float* beta = (const float*)d_in[3];
    float* ws  = (float*)d_ws;
    float* out = (float*)d_out;

    const size_t maxW  = (HGW > GGW) ? HGW : GGW;
    const size_t needA = (YWORDS + maxW) * sizeof(float);   // ~84 MB
    const size_t needB = (YWORDS + GGW) * sizeof(float);    // ~76 MB

    if (ws_size >= needA) {
        float* gG = ws + YWORDS;
        float* hg = ws + YWORDS;   // aliases gG (dead before la_scan)
        la_gram<<<PAIRS * NCH, 256, 0, stream>>>(k, gG);
        la_phase1g<<<PAIRS * NCH * 2, 256, 0, stream>>>(k, v, beta, ws, gG);
        la_scan<<<PAIRS, 512, 0, stream>>>(ws, hg);
        la_out<<<PAIRS * NCH, 512, 0, stream>>>(q, ws, hg, out);
    } else if (ws_size >= needB) {
        float* gG = ws + YWORDS;
        la_gram<<<PAIRS * NCH, 256, 0, stream>>>(k, gG);
        la_phase1g<<<PAIRS * NCH * 2, 256, 0, stream>>>(k, v, beta, ws, gG);
        la_phase2<<<PAIRS * NB2, 512, 0, stream>>>(q, ws, out);
    } else {
        la_phase1f<<<PAIRS * NCH * 2, 256, 0, stream>>>(k, v, beta, ws);
        la_phase2<<<PAIRS * NB2, 512, 0, stream>>>(q, ws, out);
    }
}